// Round 1
// baseline (958.258 us; speedup 1.0000x reference)
//
#include <hip/hip_runtime.h>

#define CH 128
#define DS 24
#define HW (DS*DS)      // 576
#define VS (DS*DS*DS)   // 13824

// ---------------------------------------------------------------------------
// K0: weight prep.  WT[k][c][96] (o-padded, zero-filled), WD[k][c][128],
// W1T[c][128].  Scattered reads, tiny (~3.2MB), runs once per launch.
// ---------------------------------------------------------------------------
__global__ __launch_bounds__(256) void prep_weights(
    const float* __restrict__ w_off, const float* __restrict__ w_def,
    const float* __restrict__ w1,
    float* __restrict__ WT, float* __restrict__ WD, float* __restrict__ W1T) {
  const int n_off = 27*128*96, n_def = 27*128*128, n_w1 = 128*128;
  const int ntot = n_off + n_def + n_w1;
  for (int i = blockIdx.x*256 + threadIdx.x; i < ntot; i += gridDim.x*256) {
    if (i < n_off) {
      int o = i % 96, c = (i/96) % 128, k = i/(96*128);
      WT[i] = (o < 81) ? w_off[(o*128 + c)*27 + k] : 0.f;
    } else if (i < n_off + n_def) {
      int j = i - n_off;
      int o = j % 128, c = (j/128) % 128, k = j/(128*128);
      WD[j] = w_def[(o*128 + c)*27 + k];
    } else {
      int j = i - n_off - n_def;
      int o = j % 128, c = j/128;
      W1T[j] = w1[o*128 + c];
    }
  }
}

// ---------------------------------------------------------------------------
// K1: depthwise 5x5x5, pad=2.  One block per (channel, z-half of 12).
// LDS slab [16 z][24 y][36 x] (x pre-padded by 2, stride 36 breaks bank
// repeats), 4 outputs/thread along x via register slide.
// ---------------------------------------------------------------------------
__global__ __launch_bounds__(256) void dw5_kernel(
    const float* __restrict__ x, const float* __restrict__ w0,
    const float* __restrict__ b0, float* __restrict__ A1) {
  const int c  = blockIdx.x >> 1;
  const int zb = (blockIdx.x & 1) * 12;
  __shared__ __align__(16) float sin_[16*24*36];
  __shared__ float sw[128];
  const int t = threadIdx.x;
  if (t < 125) sw[t] = w0[c*125 + t];
  const float* xc = x + c*VS;
  for (int i = t; i < 16*24*36; i += 256) {
    int px = i % 36;
    int y  = (i / 36) % 24;
    int pz = i / (36*24);
    int xx = px - 2;
    int zz = zb - 2 + pz;
    float v = 0.f;
    if ((unsigned)xx < 24u && (unsigned)zz < 24u) v = xc[zz*HW + y*DS + xx];
    sin_[i] = v;
  }
  __syncthreads();
  const float bias = b0[c];
  for (int g = t; g < 12*24*6; g += 256) {
    int xg = g % 6;
    int y  = (g / 6) % 24;
    int zl = g / 144;
    int x0 = xg * 4;
    float a0=0.f, a1=0.f, a2=0.f, a3=0.f;
    for (int kz = 0; kz < 5; ++kz) {
      int pz = zl + kz;
      for (int ky = 0; ky < 5; ++ky) {
        int yy = y + ky - 2;
        if ((unsigned)yy >= 24u) continue;
        const float* row = &sin_[(pz*24 + yy)*36 + x0];
        float4 r0 = *(const float4*)(row);
        float4 r1 = *(const float4*)(row+4);
        float4 r2 = *(const float4*)(row+8);
        float f[12] = {r0.x,r0.y,r0.z,r0.w, r1.x,r1.y,r1.z,r1.w,
                       r2.x,r2.y,r2.z,r2.w};
        const float* wr = &sw[(kz*5+ky)*5];
        #pragma unroll
        for (int kx = 0; kx < 5; ++kx) {
          float w = wr[kx];
          a0 = fmaf(w, f[kx],   a0);
          a1 = fmaf(w, f[kx+1], a1);
          a2 = fmaf(w, f[kx+2], a2);
          a3 = fmaf(w, f[kx+3], a3);
        }
      }
    }
    int z = zb + zl;
    int v = (z*DS + y)*DS + x0;
    *(float4*)&A1[c*VS + v] = make_float4(a0+bias, a1+bias, a2+bias, a3+bias);
  }
}

// ---------------------------------------------------------------------------
// K2: depthwise 5x5x5, dilation=3, pad=6.  Block per (channel, z-quarter of 6).
// LDS slab [18 z][24 y][36 x] (x pre-padded by 6).  Taps span 16 x-floats.
// ---------------------------------------------------------------------------
__global__ __launch_bounds__(256) void dwdil_kernel(
    const float* __restrict__ A1, const float* __restrict__ wgt,
    const float* __restrict__ bs, float* __restrict__ A2) {
  const int c  = blockIdx.x >> 2;
  const int zb = (blockIdx.x & 3) * 6;
  __shared__ __align__(16) float sin_[18*24*36];
  __shared__ float sw[128];
  const int t = threadIdx.x;
  if (t < 125) sw[t] = wgt[c*125 + t];
  const float* xc = A1 + c*VS;
  for (int i = t; i < 18*24*36; i += 256) {
    int px = i % 36;
    int y  = (i / 36) % 24;
    int pz = i / (36*24);
    int xx = px - 6;
    int zz = zb - 6 + pz;
    float v = 0.f;
    if ((unsigned)xx < 24u && (unsigned)zz < 24u) v = xc[zz*HW + y*DS + xx];
    sin_[i] = v;
  }
  __syncthreads();
  const float bias = bs[c];
  for (int g = t; g < 6*24*6; g += 256) {
    int xg = g % 6;
    int y  = (g / 6) % 24;
    int zl = g / 144;   // 0..5
    int x0 = xg * 4;
    float a0=0.f, a1=0.f, a2=0.f, a3=0.f;
    for (int kz = 0; kz < 5; ++kz) {
      int pz = zl + 3*kz;           // = (zb+zl+3kz-6) - (zb-6)
      for (int ky = 0; ky < 5; ++ky) {
        int yy = y + 3*ky - 6;
        if ((unsigned)yy >= 24u) continue;
        const float* row = &sin_[(pz*24 + yy)*36 + x0];
        float4 r0 = *(const float4*)(row);
        float4 r1 = *(const float4*)(row+4);
        float4 r2 = *(const float4*)(row+8);
        float4 r3 = *(const float4*)(row+12);
        float f[16] = {r0.x,r0.y,r0.z,r0.w, r1.x,r1.y,r1.z,r1.w,
                       r2.x,r2.y,r2.z,r2.w, r3.x,r3.y,r3.z,r3.w};
        const float* wr = &sw[(kz*5+ky)*5];
        #pragma unroll
        for (int kx = 0; kx < 5; ++kx) {
          float w = wr[kx];
          a0 = fmaf(w, f[3*kx],   a0);
          a1 = fmaf(w, f[3*kx+1], a1);
          a2 = fmaf(w, f[3*kx+2], a2);
          a3 = fmaf(w, f[3*kx+3], a3);
        }
      }
    }
    int z = zb + zl;
    int v = (z*DS + y)*DS + x0;
    *(float4*)&A2[c*VS + v] = make_float4(a0+bias, a1+bias, a2+bias, a3+bias);
  }
}

// ---------------------------------------------------------------------------
// K3: transpose A2 [128][V] -> A2t [V][128] (for coalesced trilinear gathers).
// ---------------------------------------------------------------------------
__global__ __launch_bounds__(256) void transpose_kernel(
    const float* __restrict__ A2, float* __restrict__ A2t) {
  const int vb = (blockIdx.x % 216) * 64;
  const int cb = (blockIdx.x / 216) * 64;
  __shared__ float tile[64][65];
  const int t = threadIdx.x;
  {
    int lv = t % 64, lc4 = t / 64;
    for (int r = 0; r < 16; ++r) {
      int lc = r*4 + lc4;
      tile[lc][lv] = A2[(cb+lc)*VS + vb + lv];
    }
  }
  __syncthreads();
  {
    int lc = t % 64, lv4 = t / 64;
    for (int r = 0; r < 16; ++r) {
      int lv = r*4 + lv4;
      A2t[(vb+lv)*CH + cb + lc] = tile[lc][lv];
    }
  }
}

// ---------------------------------------------------------------------------
// K4: offset conv, 3x3x3 pad=1, 128->81 (M padded to 96).  Tap-loop GEMM:
// OFF[o][v] = b_off[o] + sum_k sum_c WT[k][c][o] * shift_k(A2)[c][v]
// 64-v tile per block, c staged in halves of 64 to fit 64KB LDS.
// block 192 = 12 o-groups(8) x 16 v-groups(4).
// ---------------------------------------------------------------------------
__global__ __launch_bounds__(192) void offconv_kernel(
    const float* __restrict__ A2, const float* __restrict__ WT,
    const float* __restrict__ b_off, float* __restrict__ OFF) {
  const int vb = blockIdx.x * 64;
  __shared__ __align__(16) float Wl[64*96];   // 24.6 KB
  __shared__ __align__(16) float Bl[64*68];   // 17.4 KB
  const int t  = threadIdx.x;
  const int og = t / 16, vg = t % 16;
  const int o0 = og * 8;
  float acc[8][4];
  #pragma unroll
  for (int i = 0; i < 8; ++i)
    #pragma unroll
    for (int j = 0; j < 4; ++j) acc[i][j] = 0.f;

  for (int k = 0; k < 27; ++k) {
    const int dz = k/9 - 1, dy = (k/3)%3 - 1, dx = k%3 - 1;
    const int doff = (dz*DS + dy)*DS + dx;
    for (int chh = 0; chh < 2; ++chh) {
      __syncthreads();  // previous GEMM done before restaging
      for (int s = t; s < 64*24; s += 192) {   // stage W half
        int cl = s / 24, oq = s % 24;
        *(float4*)&Wl[cl*96 + 4*oq] =
            *(const float4*)&WT[(k*CH + chh*64 + cl)*96 + 4*oq];
      }
      for (int s = t; s < 64*16; s += 192) {   // stage B half (shifted, 0-pad)
        int cl = s / 16, vq = s % 16;
        int cg = chh*64 + cl;
        float vals[4];
        #pragma unroll
        for (int j = 0; j < 4; ++j) {
          int v = vb + 4*vq + j;
          int z = v / HW, y = (v / DS) % DS, xx = v % DS;
          int zz = z + dz, yy = y + dy, xq = xx + dx;
          float val = 0.f;
          if ((unsigned)zz < 24u && (unsigned)yy < 24u && (unsigned)xq < 24u)
            val = A2[cg*VS + v + doff];
          vals[j] = val;
        }
        *(float4*)&Bl[cl*68 + 4*vq] = make_float4(vals[0],vals[1],vals[2],vals[3]);
      }
      __syncthreads();
      for (int cl = 0; cl < 64; ++cl) {
        float4 b  = *(const float4*)&Bl[cl*68 + 4*vg];
        float4 wa = *(const float4*)&Wl[cl*96 + o0];
        float4 wb = *(const float4*)&Wl[cl*96 + o0 + 4];
        float wv[8] = {wa.x,wa.y,wa.z,wa.w, wb.x,wb.y,wb.z,wb.w};
        float bv[4] = {b.x,b.y,b.z,b.w};
        #pragma unroll
        for (int i = 0; i < 8; ++i)
          #pragma unroll
          for (int j = 0; j < 4; ++j)
            acc[i][j] = fmaf(wv[i], bv[j], acc[i][j]);
      }
    }
  }
  #pragma unroll
  for (int i = 0; i < 8; ++i) {
    int o = o0 + i;
    if (o < 81) {
      float bias = b_off[o];
      *(float4*)&OFF[o*VS + vb + 4*vg] =
          make_float4(acc[i][0]+bias, acc[i][1]+bias, acc[i][2]+bias, acc[i][3]+bias);
    }
  }
}

// ---------------------------------------------------------------------------
// K5: deformable conv 3x3x3 (DCNv1), 128->128.  Per tap: compute per-v
// trilinear meta (floor/frac -> 8 corner weights+indices), gather-stage
// B[c][v] from A2t (coalesced 16B channel reads), then tap GEMM with
// WD[k][c][o].  c staged in halves of 64.  block 256 = 16 og x 16 vg.
// ---------------------------------------------------------------------------
__global__ __launch_bounds__(256) void deform_kernel(
    const float* __restrict__ A2t, const float* __restrict__ OFF,
    const float* __restrict__ WD, const float* __restrict__ b_def,
    float* __restrict__ DEF) {
  const int vb = blockIdx.x * 64;
  __shared__ __align__(16) float Wl[64*128];  // 32 KB
  __shared__ __align__(16) float Bl[64*68];   // 17.4 KB
  __shared__ float mF[64][3];
  __shared__ int   mI[64][3];
  __shared__ float W8[64][8];
  __shared__ int   I8[64][8];
  const int t  = threadIdx.x;
  const int og = t / 16, vg = t % 16;
  const int o0 = og * 8;
  float acc[8][4];
  #pragma unroll
  for (int i = 0; i < 8; ++i)
    #pragma unroll
    for (int j = 0; j < 4; ++j) acc[i][j] = 0.f;

  for (int k = 0; k < 27; ++k) {
    __syncthreads();                 // previous tap's GEMM + gathers done
    if (t < 64) {                    // meta A: floor/frac per axis
      int v = vb + t;
      int z = v / HW, y = (v / DS) % DS, xx = v % DS;
      float bases[3] = {(float)z, (float)y, (float)xx};
      int kd[3] = {k/9 - 1, (k/3)%3 - 1, k%3 - 1};
      #pragma unroll
      for (int a = 0; a < 3; ++a) {
        float coord = bases[a] + (float)kd[a] + OFF[(3*k + a)*VS + v];
        float fl = floorf(coord);
        mI[t][a] = (int)fl;
        mF[t][a] = coord - fl;
      }
    }
    __syncthreads();
    for (int s = t; s < 512; s += 256) {   // meta B: 8 corners per v
      int vl = s / 8, corner = s % 8;
      int ca = (corner >> 2) & 1, cb = (corner >> 1) & 1, cc = corner & 1;
      int zi = mI[vl][0] + ca, yi = mI[vl][1] + cb, xi = mI[vl][2] + cc;
      float fz = mF[vl][0], fy = mF[vl][1], fx = mF[vl][2];
      float w = (ca ? fz : 1.f-fz) * (cb ? fy : 1.f-fy) * (cc ? fx : 1.f-fx);
      bool valid = ((unsigned)zi < 24u) && ((unsigned)yi < 24u) && ((unsigned)xi < 24u);
      W8[vl][corner] = valid ? w : 0.f;
      I8[vl][corner] = valid ? (zi*DS + yi)*DS + xi : 0;
    }
    __syncthreads();
    for (int chh = 0; chh < 2; ++chh) {
      if (chh) __syncthreads();      // half-0 GEMM done before restage
      for (int s = t; s < 64*32; s += 256) {   // stage W half
        int cl = s / 32, oq = s % 32;
        *(float4*)&Wl[cl*128 + 4*oq] =
            *(const float4*)&WD[(k*CH + chh*64 + cl)*CH + 4*oq];
      }
      {                                         // gather-stage B half
        int cq = t % 16, vi = t / 16;
        for (int vp = 0; vp < 4; ++vp) {
          int vl = vp*16 + vi;
          float g0=0.f, g1=0.f, g2=0.f, g3=0.f;
          #pragma unroll
          for (int corner = 0; corner < 8; ++corner) {
            float w = W8[vl][corner];
            const float4 g = *(const float4*)&A2t[I8[vl][corner]*CH + chh*64 + 4*cq];
            g0 = fmaf(w, g.x, g0); g1 = fmaf(w, g.y, g1);
            g2 = fmaf(w, g.z, g2); g3 = fmaf(w, g.w, g3);
          }
          Bl[(4*cq+0)*68 + vl] = g0;
          Bl[(4*cq+1)*68 + vl] = g1;
          Bl[(4*cq+2)*68 + vl] = g2;
          Bl[(4*cq+3)*68 + vl] = g3;
        }
      }
      __syncthreads();
      for (int cl = 0; cl < 64; ++cl) {
        float4 b  = *(const float4*)&Bl[cl*68 + 4*vg];
        float4 wa = *(const float4*)&Wl[cl*128 + o0];
        float4 wb = *(const float4*)&Wl[cl*128 + o0 + 4];
        float wv[8] = {wa.x,wa.y,wa.z,wa.w, wb.x,wb.y,wb.z,wb.w};
        float bv[4] = {b.x,b.y,b.z,b.w};
        #pragma unroll
        for (int i = 0; i < 8; ++i)
          #pragma unroll
          for (int j = 0; j < 4; ++j)
            acc[i][j] = fmaf(wv[i], bv[j], acc[i][j]);
      }
    }
  }
  #pragma unroll
  for (int i = 0; i < 8; ++i) {
    int o = o0 + i;
    float bias = b_def[o];
    *(float4*)&DEF[o*VS + vb + 4*vg] =
        make_float4(acc[i][0]+bias, acc[i][1]+bias, acc[i][2]+bias, acc[i][3]+bias);
  }
}

// ---------------------------------------------------------------------------
// K6: 1x1x1 conv (128->128) + bias + elementwise multiply with x.
// ---------------------------------------------------------------------------
__global__ __launch_bounds__(256) void pw_mul_kernel(
    const float* __restrict__ DEF, const float* __restrict__ W1T,
    const float* __restrict__ b1, const float* __restrict__ x,
    float* __restrict__ out) {
  const int vb = blockIdx.x * 64;
  __shared__ __align__(16) float Wl[64*128];
  __shared__ __align__(16) float Bl[64*68];
  const int t  = threadIdx.x;
  const int og = t / 16, vg = t % 16;
  const int o0 = og * 8;
  float acc[8][4];
  #pragma unroll
  for (int i = 0; i < 8; ++i)
    #pragma unroll
    for (int j = 0; j < 4; ++j) acc[i][j] = 0.f;

  for (int chh = 0; chh < 2; ++chh) {
    if (chh) __syncthreads();
    for (int s = t; s < 64*32; s += 256) {
      int cl = s / 32, oq = s % 32;
      *(float4*)&Wl[cl*128 + 4*oq] =
          *(const float4*)&W1T[(chh*64 + cl)*CH + 4*oq];
    }
    for (int s = t; s < 64*16; s += 256) {
      int cl = s / 16, vq = s % 16;
      *(float4*)&Bl[cl*68 + 4*vq] =
          *(const float4*)&DEF[(chh*64 + cl)*VS + vb + 4*vq];
    }
    __syncthreads();
    for (int cl = 0; cl < 64; ++cl) {
      float4 b  = *(const float4*)&Bl[cl*68 + 4*vg];
      float4 wa = *(const float4*)&Wl[cl*128 + o0];
      float4 wb = *(const float4*)&Wl[cl*128 + o0 + 4];
      float wv[8] = {wa.x,wa.y,wa.z,wa.w, wb.x,wb.y,wb.z,wb.w};
      float bv[4] = {b.x,b.y,b.z,b.w};
      #pragma unroll
      for (int i = 0; i < 8; ++i)
        #pragma unroll
        for (int j = 0; j < 4; ++j)
          acc[i][j] = fmaf(wv[i], bv[j], acc[i][j]);
    }
  }
  #pragma unroll
  for (int i = 0; i < 8; ++i) {
    int o = o0 + i;
    float bias = b1[o];
    float4 xs = *(const float4*)&x[o*VS + vb + 4*vg];
    *(float4*)&out[o*VS + vb + 4*vg] =
        make_float4(xs.x*(acc[i][0]+bias), xs.y*(acc[i][1]+bias),
                    xs.z*(acc[i][2]+bias), xs.w*(acc[i][3]+bias));
  }
}

// ---------------------------------------------------------------------------
extern "C" void kernel_launch(void* const* d_in, const int* in_sizes, int n_in,
                              void* d_out, int out_size, void* d_ws, size_t ws_size,
                              hipStream_t stream) {
  (void)in_sizes; (void)n_in; (void)out_size; (void)ws_size;
  const float* x     = (const float*)d_in[0];
  const float* w0    = (const float*)d_in[1];
  const float* b0    = (const float*)d_in[2];
  const float* wsw   = (const float*)d_in[3];
  const float* bs    = (const float*)d_in[4];
  const float* w_off = (const float*)d_in[5];
  const float* b_off = (const float*)d_in[6];
  const float* w_def = (const float*)d_in[7];
  const float* b_def = (const float*)d_in[8];
  const float* w1    = (const float*)d_in[9];
  const float* b1    = (const float*)d_in[10];
  float* out = (float*)d_out;

  float* wsf = (float*)d_ws;
  float* A1  = wsf;                       // 1769472 floats (also reused as OFF)
  float* A2  = A1  + 1769472;
  float* A2t = A2  + 1769472;
  float* DEF = A2t + 1769472;
  float* WT  = DEF + 1769472;             // 27*128*96  = 331776
  float* WD  = WT  + 331776;              // 27*128*128 = 442368
  float* W1T = WD  + 442368;              // 128*128    = 16384
  float* OFF = A1;                        // A1 dead after dwdil; 81*VS fits

  prep_weights   <<<1024, 256, 0, stream>>>(w_off, w_def, w1, WT, WD, W1T);
  dw5_kernel     <<<256,  256, 0, stream>>>(x, w0, b0, A1);
  dwdil_kernel   <<<512,  256, 0, stream>>>(A1, wsw, bs, A2);
  transpose_kernel<<<432, 256, 0, stream>>>(A2, A2t);
  offconv_kernel <<<216,  192, 0, stream>>>(A2, WT, b_off, OFF);
  deform_kernel  <<<216,  256, 0, stream>>>(A2t, OFF, WD, b_def, DEF);
  pw_mul_kernel  <<<216,  256, 0, stream>>>(DEF, W1T, b1, x, out);
}

// Round 2
// 705.281 us; speedup vs baseline: 1.3587x; 1.3587x over previous
//
#include <hip/hip_runtime.h>

#define CH 128
#define DS 24
#define HW (DS*DS)      // 576
#define VS (DS*DS*DS)   // 13824

// ---------------------------------------------------------------------------
// K0: weight prep.  WT[k][c][96] (o-padded, zero-filled), WD[k][c][128],
// W1T[c][128].
// ---------------------------------------------------------------------------
__global__ __launch_bounds__(256) void prep_weights(
    const float* __restrict__ w_off, const float* __restrict__ w_def,
    const float* __restrict__ w1,
    float* __restrict__ WT, float* __restrict__ WD, float* __restrict__ W1T) {
  const int n_off = 27*128*96, n_def = 27*128*128, n_w1 = 128*128;
  const int ntot = n_off + n_def + n_w1;
  for (int i = blockIdx.x*256 + threadIdx.x; i < ntot; i += gridDim.x*256) {
    if (i < n_off) {
      int o = i % 96, c = (i/96) % 128, k = i/(96*128);
      WT[i] = (o < 81) ? w_off[(o*128 + c)*27 + k] : 0.f;
    } else if (i < n_off + n_def) {
      int j = i - n_off;
      int o = j % 128, c = (j/128) % 128, k = j/(128*128);
      WD[j] = w_def[(o*128 + c)*27 + k];
    } else {
      int j = i - n_off - n_def;
      int o = j % 128, c = j/128;
      W1T[j] = w1[o*128 + c];
    }
  }
}

// ---------------------------------------------------------------------------
// K0b: bias-init OFF[81][V] and DEF[128][V] (split-K blocks atomicAdd into
// these; d_ws is re-poisoned 0xAA before every launch so init is mandatory).
// ---------------------------------------------------------------------------
__global__ __launch_bounds__(256) void init_bias(
    const float* __restrict__ b_off, const float* __restrict__ b_def,
    float* __restrict__ OFF, float* __restrict__ DEF) {
  const int n1 = 81*VS;
  const int n2 = 128*VS;
  int i = blockIdx.x*256 + threadIdx.x;
  if (i < n1) OFF[i] = b_off[i / VS];
  else if (i < n1 + n2) { int j = i - n1; DEF[j] = b_def[j / VS]; }
}

// ---------------------------------------------------------------------------
// K1: depthwise 5x5x5, pad=2.  One block per (channel, z-half of 12).
// ---------------------------------------------------------------------------
__global__ __launch_bounds__(256) void dw5_kernel(
    const float* __restrict__ x, const float* __restrict__ w0,
    const float* __restrict__ b0, float* __restrict__ A1) {
  const int c  = blockIdx.x >> 1;
  const int zb = (blockIdx.x & 1) * 12;
  __shared__ __align__(16) float sin_[16*24*36];
  __shared__ float sw[128];
  const int t = threadIdx.x;
  if (t < 125) sw[t] = w0[c*125 + t];
  const float* xc = x + c*VS;
  for (int i = t; i < 16*24*36; i += 256) {
    int px = i % 36;
    int y  = (i / 36) % 24;
    int pz = i / (36*24);
    int xx = px - 2;
    int zz = zb - 2 + pz;
    float v = 0.f;
    if ((unsigned)xx < 24u && (unsigned)zz < 24u) v = xc[zz*HW + y*DS + xx];
    sin_[i] = v;
  }
  __syncthreads();
  const float bias = b0[c];
  for (int g = t; g < 12*24*6; g += 256) {
    int xg = g % 6;
    int y  = (g / 6) % 24;
    int zl = g / 144;
    int x0 = xg * 4;
    float a0=0.f, a1=0.f, a2=0.f, a3=0.f;
    for (int kz = 0; kz < 5; ++kz) {
      int pz = zl + kz;
      for (int ky = 0; ky < 5; ++ky) {
        int yy = y + ky - 2;
        if ((unsigned)yy >= 24u) continue;
        const float* row = &sin_[(pz*24 + yy)*36 + x0];
        float4 r0 = *(const float4*)(row);
        float4 r1 = *(const float4*)(row+4);
        float4 r2 = *(const float4*)(row+8);
        float f[12] = {r0.x,r0.y,r0.z,r0.w, r1.x,r1.y,r1.z,r1.w,
                       r2.x,r2.y,r2.z,r2.w};
        const float* wr = &sw[(kz*5+ky)*5];
        #pragma unroll
        for (int kx = 0; kx < 5; ++kx) {
          float w = wr[kx];
          a0 = fmaf(w, f[kx],   a0);
          a1 = fmaf(w, f[kx+1], a1);
          a2 = fmaf(w, f[kx+2], a2);
          a3 = fmaf(w, f[kx+3], a3);
        }
      }
    }
    int z = zb + zl;
    int v = (z*DS + y)*DS + x0;
    *(float4*)&A1[c*VS + v] = make_float4(a0+bias, a1+bias, a2+bias, a3+bias);
  }
}

// ---------------------------------------------------------------------------
// K2: depthwise 5x5x5, dilation=3, pad=6.  Block per (channel, z-quarter).
// ---------------------------------------------------------------------------
__global__ __launch_bounds__(256) void dwdil_kernel(
    const float* __restrict__ A1, const float* __restrict__ wgt,
    const float* __restrict__ bs, float* __restrict__ A2) {
  const int c  = blockIdx.x >> 2;
  const int zb = (blockIdx.x & 3) * 6;
  __shared__ __align__(16) float sin_[18*24*36];
  __shared__ float sw[128];
  const int t = threadIdx.x;
  if (t < 125) sw[t] = wgt[c*125 + t];
  const float* xc = A1 + c*VS;
  for (int i = t; i < 18*24*36; i += 256) {
    int px = i % 36;
    int y  = (i / 36) % 24;
    int pz = i / (36*24);
    int xx = px - 6;
    int zz = zb - 6 + pz;
    float v = 0.f;
    if ((unsigned)xx < 24u && (unsigned)zz < 24u) v = xc[zz*HW + y*DS + xx];
    sin_[i] = v;
  }
  __syncthreads();
  const float bias = bs[c];
  for (int g = t; g < 6*24*6; g += 256) {
    int xg = g % 6;
    int y  = (g / 6) % 24;
    int zl = g / 144;   // 0..5
    int x0 = xg * 4;
    float a0=0.f, a1=0.f, a2=0.f, a3=0.f;
    for (int kz = 0; kz < 5; ++kz) {
      int pz = zl + 3*kz;
      for (int ky = 0; ky < 5; ++ky) {
        int yy = y + 3*ky - 6;
        if ((unsigned)yy >= 24u) continue;
        const float* row = &sin_[(pz*24 + yy)*36 + x0];
        float4 r0 = *(const float4*)(row);
        float4 r1 = *(const float4*)(row+4);
        float4 r2 = *(const float4*)(row+8);
        float4 r3 = *(const float4*)(row+12);
        float f[16] = {r0.x,r0.y,r0.z,r0.w, r1.x,r1.y,r1.z,r1.w,
                       r2.x,r2.y,r2.z,r2.w, r3.x,r3.y,r3.z,r3.w};
        const float* wr = &sw[(kz*5+ky)*5];
        #pragma unroll
        for (int kx = 0; kx < 5; ++kx) {
          float w = wr[kx];
          a0 = fmaf(w, f[3*kx],   a0);
          a1 = fmaf(w, f[3*kx+1], a1);
          a2 = fmaf(w, f[3*kx+2], a2);
          a3 = fmaf(w, f[3*kx+3], a3);
        }
      }
    }
    int z = zb + zl;
    int v = (z*DS + y)*DS + x0;
    *(float4*)&A2[c*VS + v] = make_float4(a0+bias, a1+bias, a2+bias, a3+bias);
  }
}

// ---------------------------------------------------------------------------
// K3: transpose A2 [128][V] -> A2t [V][128].
// ---------------------------------------------------------------------------
__global__ __launch_bounds__(256) void transpose_kernel(
    const float* __restrict__ A2, float* __restrict__ A2t) {
  const int vb = (blockIdx.x % 216) * 64;
  const int cb = (blockIdx.x / 216) * 64;
  __shared__ float tile[64][65];
  const int t = threadIdx.x;
  {
    int lv = t % 64, lc4 = t / 64;
    for (int r = 0; r < 16; ++r) {
      int lc = r*4 + lc4;
      tile[lc][lv] = A2[(cb+lc)*VS + vb + lv];
    }
  }
  __syncthreads();
  {
    int lc = t % 64, lv4 = t / 64;
    for (int r = 0; r < 16; ++r) {
      int lv = r*4 + lv4;
      A2t[(vb+lv)*CH + cb + lc] = tile[lc][lv];
    }
  }
}

// ---------------------------------------------------------------------------
// K4: offset conv, split-K: grid = 216 v-tiles x 3 tap-groups (9 taps each).
// Accumulates into bias-initialized OFF via atomicAdd (device-scope, G12).
// LDS: Wl 24KB + Bl 16KB = 40KB -> 4 blocks/CU.
// ---------------------------------------------------------------------------
__global__ __launch_bounds__(192) void offconv_kernel(
    const float* __restrict__ A2, const float* __restrict__ WT,
    float* __restrict__ OFF) {
  const int vb = (blockIdx.x % 216) * 64;
  const int kg = blockIdx.x / 216;          // 0..2
  __shared__ __align__(16) float Wl[64*96];   // 24.6 KB
  __shared__ __align__(16) float Bl[64*64];   // 16 KB
  const int t  = threadIdx.x;
  const int og = t / 16, vg = t % 16;
  const int o0 = og * 8;
  float acc[8][4];
  #pragma unroll
  for (int i = 0; i < 8; ++i)
    #pragma unroll
    for (int j = 0; j < 4; ++j) acc[i][j] = 0.f;

  for (int kk = 0; kk < 9; ++kk) {
    const int k = kg*9 + kk;
    const int dz = k/9 - 1, dy = (k/3)%3 - 1, dx = k%3 - 1;
    const int doff = (dz*DS + dy)*DS + dx;
    for (int chh = 0; chh < 2; ++chh) {
      __syncthreads();  // previous GEMM done before restaging
      for (int s = t; s < 64*24; s += 192) {   // stage W half
        int cl = s / 24, oq = s % 24;
        *(float4*)&Wl[cl*96 + 4*oq] =
            *(const float4*)&WT[(k*CH + chh*64 + cl)*96 + 4*oq];
      }
      for (int s = t; s < 64*16; s += 192) {   // stage B half (shifted, 0-pad)
        int cl = s / 16, vq = s % 16;
        int cg = chh*64 + cl;
        float vals[4];
        #pragma unroll
        for (int j = 0; j < 4; ++j) {
          int v = vb + 4*vq + j;
          int z = v / HW, y = (v / DS) % DS, xx = v % DS;
          int zz = z + dz, yy = y + dy, xq = xx + dx;
          float val = 0.f;
          if ((unsigned)zz < 24u && (unsigned)yy < 24u && (unsigned)xq < 24u)
            val = A2[cg*VS + v + doff];
          vals[j] = val;
        }
        *(float4*)&Bl[cl*64 + 4*vq] = make_float4(vals[0],vals[1],vals[2],vals[3]);
      }
      __syncthreads();
      for (int cl = 0; cl < 64; ++cl) {
        float4 b  = *(const float4*)&Bl[cl*64 + 4*vg];
        float4 wa = *(const float4*)&Wl[cl*96 + o0];
        float4 wb = *(const float4*)&Wl[cl*96 + o0 + 4];
        float wv[8] = {wa.x,wa.y,wa.z,wa.w, wb.x,wb.y,wb.z,wb.w};
        float bv[4] = {b.x,b.y,b.z,b.w};
        #pragma unroll
        for (int i = 0; i < 8; ++i)
          #pragma unroll
          for (int j = 0; j < 4; ++j)
            acc[i][j] = fmaf(wv[i], bv[j], acc[i][j]);
      }
    }
  }
  #pragma unroll
  for (int i = 0; i < 8; ++i) {
    int o = o0 + i;
    if (o < 81) {
      #pragma unroll
      for (int j = 0; j < 4; ++j)
        atomicAdd(&OFF[o*VS + vb + 4*vg + j], acc[i][j]);
    }
  }
}

// ---------------------------------------------------------------------------
// K5: deformable conv, split-K: grid = 216 v-tiles x 9 tap-groups (3 taps).
// Bl uses column-rotation swizzle col' = (col + 4*(c>>2)) & 63: the gather's
// scalar column-writes land 2 lanes/bank (free, m136) and GEMM b128 reads
// stay 16B-aligned.  LDS 52KB -> 3 blocks/CU.  atomicAdd into DEF.
// ---------------------------------------------------------------------------
__global__ __launch_bounds__(256) void deform_kernel(
    const float* __restrict__ A2t, const float* __restrict__ OFF,
    const float* __restrict__ WD, float* __restrict__ DEF) {
  const int vb = (blockIdx.x % 216) * 64;
  const int kg = blockIdx.x / 216;          // 0..8
  __shared__ __align__(16) float Wl[64*128];  // 32 KB
  __shared__ __align__(16) float Bl[64*64];   // 16 KB (swizzled)
  __shared__ float W8[64][8];
  __shared__ int   I8[64][8];
  const int t  = threadIdx.x;
  const int og = t / 16, vg = t % 16;
  const int o0 = og * 8;
  float acc[8][4];
  #pragma unroll
  for (int i = 0; i < 8; ++i)
    #pragma unroll
    for (int j = 0; j < 4; ++j) acc[i][j] = 0.f;

  for (int kk = 0; kk < 3; ++kk) {
    const int k = kg*3 + kk;
    __syncthreads();                 // previous tap fully consumed
    if (t < 64) {                    // trilinear meta: 8 corner weights+idx
      int v = vb + t;
      int z = v / HW, y = (v / DS) % DS, xx = v % DS;
      float cz = (float)(z  + k/9     - 1) + OFF[(3*k + 0)*VS + v];
      float cy = (float)(y  + (k/3)%3 - 1) + OFF[(3*k + 1)*VS + v];
      float cx = (float)(xx + k%3     - 1) + OFF[(3*k + 2)*VS + v];
      float fz = floorf(cz), fy = floorf(cy), fx = floorf(cx);
      int iz = (int)fz, iy = (int)fy, ix = (int)fx;
      float rz = cz - fz, ry = cy - fy, rx = cx - fx;
      #pragma unroll
      for (int corner = 0; corner < 8; ++corner) {
        int ca = corner >> 2, cb = (corner >> 1) & 1, cc = corner & 1;
        int zi = iz + ca, yi = iy + cb, xi = ix + cc;
        float w = (ca ? rz : 1.f-rz) * (cb ? ry : 1.f-ry) * (cc ? rx : 1.f-rx);
        bool valid = ((unsigned)zi < 24u) && ((unsigned)yi < 24u) && ((unsigned)xi < 24u);
        W8[t][corner] = valid ? w : 0.f;
        I8[t][corner] = valid ? (zi*DS + yi)*DS + xi : 0;
      }
    }
    __syncthreads();
    for (int chh = 0; chh < 2; ++chh) {
      if (chh) __syncthreads();      // half-0 GEMM done before restage
      for (int s = t; s < 64*32; s += 256) {   // stage W half
        int cl = s / 32, oq = s % 32;
        *(float4*)&Wl[cl*128 + 4*oq] =
            *(const float4*)&WD[(k*CH + chh*64 + cl)*CH + 4*oq];
      }
      {                                         // gather-stage B half
        int cq = t % 16, vi = t / 16;
        for (int vp = 0; vp < 4; ++vp) {
          int vl = vp*16 + vi;
          float g0=0.f, g1=0.f, g2=0.f, g3=0.f;
          #pragma unroll
          for (int corner = 0; corner < 8; ++corner) {
            float w = W8[vl][corner];
            const float4 g = *(const float4*)&A2t[I8[vl][corner]*CH + chh*64 + 4*cq];
            g0 = fmaf(w, g.x, g0); g1 = fmaf(w, g.y, g1);
            g2 = fmaf(w, g.z, g2); g3 = fmaf(w, g.w, g3);
          }
          int sw = (vl + 4*cq) & 63;           // rot by 4*(row>>2), row=4cq+j
          Bl[(4*cq+0)*64 + sw] = g0;
          Bl[(4*cq+1)*64 + sw] = g1;
          Bl[(4*cq+2)*64 + sw] = g2;
          Bl[(4*cq+3)*64 + sw] = g3;
        }
      }
      __syncthreads();
      for (int cl = 0; cl < 64; ++cl) {
        int sw = (4*vg + 4*(cl >> 2)) & 63;
        float4 b  = *(const float4*)&Bl[cl*64 + sw];
        float4 wa = *(const float4*)&Wl[cl*128 + o0];
        float4 wb = *(const float4*)&Wl[cl*128 + o0 + 4];
        float wv[8] = {wa.x,wa.y,wa.z,wa.w, wb.x,wb.y,wb.z,wb.w};
        float bv[4] = {b.x,b.y,b.z,b.w};
        #pragma unroll
        for (int i = 0; i < 8; ++i)
          #pragma unroll
          for (int j = 0; j < 4; ++j)
            acc[i][j] = fmaf(wv[i], bv[j], acc[i][j]);
      }
    }
  }
  #pragma unroll
  for (int i = 0; i < 8; ++i) {
    int o = o0 + i;
    #pragma unroll
    for (int j = 0; j < 4; ++j)
      atomicAdd(&DEF[o*VS + vb + 4*vg + j], acc[i][j]);
  }
}

// ---------------------------------------------------------------------------
// K6: 1x1x1 conv + bias + multiply, 32-v tiles -> 432 blocks.
// block 256 = 32 og(4 o) x 8 vg(4 v).  LDS 36KB -> 4 blocks/CU.
// ---------------------------------------------------------------------------
__global__ __launch_bounds__(256) void pw_mul_kernel(
    const float* __restrict__ DEF, const float* __restrict__ W1T,
    const float* __restrict__ b1, const float* __restrict__ x,
    float* __restrict__ out) {
  const int vb = blockIdx.x * 32;
  __shared__ __align__(16) float Wl[64*128];  // 32 KB
  __shared__ __align__(16) float Bl[64*32];   // 8 KB
  const int t  = threadIdx.x;
  const int og = t / 8, vg = t % 8;
  const int o0 = og * 4;
  float acc[4][4];
  #pragma unroll
  for (int i = 0; i < 4; ++i)
    #pragma unroll
    for (int j = 0; j < 4; ++j) acc[i][j] = 0.f;

  for (int chh = 0; chh < 2; ++chh) {
    if (chh) __syncthreads();
    for (int s = t; s < 64*32; s += 256) {
      int cl = s / 32, oq = s % 32;
      *(float4*)&Wl[cl*128 + 4*oq] =
          *(const float4*)&W1T[(chh*64 + cl)*CH + 4*oq];
    }
    for (int s = t; s < 64*8; s += 256) {
      int cl = s / 8, vq = s % 8;
      *(float4*)&Bl[cl*32 + 4*vq] =
          *(const float4*)&DEF[(chh*64 + cl)*VS + vb + 4*vq];
    }
    __syncthreads();
    for (int cl = 0; cl < 64; ++cl) {
      float4 b  = *(const float4*)&Bl[cl*32 + 4*vg];
      float4 w  = *(const float4*)&Wl[cl*128 + o0];
      float wv[4] = {w.x,w.y,w.z,w.w};
      float bv[4] = {b.x,b.y,b.z,b.w};
      #pragma unroll
      for (int i = 0; i < 4; ++i)
        #pragma unroll
        for (int j = 0; j < 4; ++j)
          acc[i][j] = fmaf(wv[i], bv[j], acc[i][j]);
    }
  }
  #pragma unroll
  for (int i = 0; i < 4; ++i) {
    int o = o0 + i;
    float bias = b1[o];
    float4 xs = *(const float4*)&x[o*VS + vb + 4*vg];
    *(float4*)&out[o*VS + vb + 4*vg] =
        make_float4(xs.x*(acc[i][0]+bias), xs.y*(acc[i][1]+bias),
                    xs.z*(acc[i][2]+bias), xs.w*(acc[i][3]+bias));
  }
}

// ---------------------------------------------------------------------------
extern "C" void kernel_launch(void* const* d_in, const int* in_sizes, int n_in,
                              void* d_out, int out_size, void* d_ws, size_t ws_size,
                              hipStream_t stream) {
  (void)in_sizes; (void)n_in; (void)out_size; (void)ws_size;
  const float* x     = (const float*)d_in[0];
  const float* w0    = (const float*)d_in[1];
  const float* b0    = (const float*)d_in[2];
  const float* wsw   = (const float*)d_in[3];
  const float* bs    = (const float*)d_in[4];
  const float* w_off = (const float*)d_in[5];
  const float* b_off = (const float*)d_in[6];
  const float* w_def = (const float*)d_in[7];
  const float* b_def = (const float*)d_in[8];
  const float* w1    = (const float*)d_in[9];
  const float* b1    = (const float*)d_in[10];
  float* out = (float*)d_out;

  float* wsf = (float*)d_ws;
  float* A1  = wsf;                       // 1769472 floats (reused as OFF)
  float* A2  = A1  + 1769472;
  float* A2t = A2  + 1769472;
  float* DEF = A2t + 1769472;
  float* WT  = DEF + 1769472;             // 27*128*96  = 331776
  float* WD  = WT  + 331776;              // 27*128*128 = 442368
  float* W1T = WD  + 442368;              // 128*128    = 16384
  float* OFF = A1;                        // A1 dead after dwdil

  prep_weights    <<<1024,  256, 0, stream>>>(w_off, w_def, w1, WT, WD, W1T);
  dw5_kernel      <<<256,   256, 0, stream>>>(x, w0, b0, A1);
  dwdil_kernel    <<<512,   256, 0, stream>>>(A1, wsw, bs, A2);
  init_bias       <<<11286, 256, 0, stream>>>(b_off, b_def, OFF, DEF);
  transpose_kernel<<<432,   256, 0, stream>>>(A2, A2t);
  offconv_kernel  <<<648,   192, 0, stream>>>(A2, WT, OFF);
  deform_kernel   <<<1944,  256, 0, stream>>>(A2t, OFF, WD, DEF);
  pw_mul_kernel   <<<432,   256, 0, stream>>>(DEF, W1T, b1, x, out);
}

// Round 3
// 377.559 us; speedup vs baseline: 2.5380x; 1.8680x over previous
//
#include <hip/hip_runtime.h>

#define CH 128
#define DS 24
#define HW (DS*DS)      // 576
#define VS (DS*DS*DS)   // 13824

typedef __attribute__((ext_vector_type(8))) short  bf16x8;
typedef __attribute__((ext_vector_type(4))) float  f32x4;

__device__ __forceinline__ unsigned short f2bf(float f) {
  union { float f; unsigned u; } v; v.f = f;
  unsigned r = v.u + 0x7FFFu + ((v.u >> 16) & 1u);   // RNE
  return (unsigned short)(r >> 16);
}

// ---------------------------------------------------------------------------
// K0: weight prep.  WTh[k][96 o][128 c] bf16 (o 81..95 zero), WDh[k][128 o]
// [128 c] bf16, W1T[c][128 o] fp32.
// ---------------------------------------------------------------------------
__global__ __launch_bounds__(256) void prep_weights(
    const float* __restrict__ w_off, const float* __restrict__ w_def,
    const float* __restrict__ w1,
    unsigned short* __restrict__ WTh, unsigned short* __restrict__ WDh,
    float* __restrict__ W1T) {
  const int n1 = 27*96*128, n2 = 27*128*128, n3 = 128*128;
  const int ntot = n1 + n2 + n3;
  for (int i = blockIdx.x*256 + threadIdx.x; i < ntot; i += gridDim.x*256) {
    if (i < n1) {
      int c = i & 127, o = (i >> 7) % 96, k = i / (96*128);
      WTh[i] = (o < 81) ? f2bf(w_off[(o*128 + c)*27 + k]) : (unsigned short)0;
    } else if (i < n1 + n2) {
      int j = i - n1;
      int c = j & 127, o = (j >> 7) & 127, k = j >> 14;
      WDh[j] = f2bf(w_def[(o*128 + c)*27 + k]);
    } else {
      int j = i - n1 - n2;
      int o = j & 127, c = j >> 7;
      W1T[j] = w1[o*128 + c];
    }
  }
}

// ---------------------------------------------------------------------------
// K0b: bias-init OFF[81][V] and DEF[128][V] (split-K atomicAdd targets).
// ---------------------------------------------------------------------------
__global__ __launch_bounds__(256) void init_bias(
    const float* __restrict__ b_off, const float* __restrict__ b_def,
    float* __restrict__ OFF, float* __restrict__ DEF) {
  const int n1 = 81*VS;
  const int n2 = 128*VS;
  int i = blockIdx.x*256 + threadIdx.x;
  if (i < n1) OFF[i] = b_off[i / VS];
  else if (i < n1 + n2) { int j = i - n1; DEF[j] = b_def[j / VS]; }
}

// ---------------------------------------------------------------------------
// K1: depthwise 5x5x5, pad=2.  One block per (channel, z-half of 12).
// ---------------------------------------------------------------------------
__global__ __launch_bounds__(256) void dw5_kernel(
    const float* __restrict__ x, const float* __restrict__ w0,
    const float* __restrict__ b0, float* __restrict__ A1) {
  const int c  = blockIdx.x >> 1;
  const int zb = (blockIdx.x & 1) * 12;
  __shared__ __align__(16) float sin_[16*24*36];
  __shared__ float sw[128];
  const int t = threadIdx.x;
  if (t < 125) sw[t] = w0[c*125 + t];
  const float* xc = x + c*VS;
  for (int i = t; i < 16*24*36; i += 256) {
    int px = i % 36;
    int y  = (i / 36) % 24;
    int pz = i / (36*24);
    int xx = px - 2;
    int zz = zb - 2 + pz;
    float v = 0.f;
    if ((unsigned)xx < 24u && (unsigned)zz < 24u) v = xc[zz*HW + y*DS + xx];
    sin_[i] = v;
  }
  __syncthreads();
  const float bias = b0[c];
  for (int g = t; g < 12*24*6; g += 256) {
    int xg = g % 6;
    int y  = (g / 6) % 24;
    int zl = g / 144;
    int x0 = xg * 4;
    float a0=0.f, a1=0.f, a2=0.f, a3=0.f;
    for (int kz = 0; kz < 5; ++kz) {
      int pz = zl + kz;
      for (int ky = 0; ky < 5; ++ky) {
        int yy = y + ky - 2;
        if ((unsigned)yy >= 24u) continue;
        const float* row = &sin_[(pz*24 + yy)*36 + x0];
        float4 r0 = *(const float4*)(row);
        float4 r1 = *(const float4*)(row+4);
        float4 r2 = *(const float4*)(row+8);
        float f[12] = {r0.x,r0.y,r0.z,r0.w, r1.x,r1.y,r1.z,r1.w,
                       r2.x,r2.y,r2.z,r2.w};
        const float* wr = &sw[(kz*5+ky)*5];
        #pragma unroll
        for (int kx = 0; kx < 5; ++kx) {
          float w = wr[kx];
          a0 = fmaf(w, f[kx],   a0);
          a1 = fmaf(w, f[kx+1], a1);
          a2 = fmaf(w, f[kx+2], a2);
          a3 = fmaf(w, f[kx+3], a3);
        }
      }
    }
    int z = zb + zl;
    int v = (z*DS + y)*DS + x0;
    *(float4*)&A1[c*VS + v] = make_float4(a0+bias, a1+bias, a2+bias, a3+bias);
  }
}

// ---------------------------------------------------------------------------
// K2: depthwise 5x5x5, dilation=3, pad=6.  Block per (channel, z-quarter).
// ---------------------------------------------------------------------------
__global__ __launch_bounds__(256) void dwdil_kernel(
    const float* __restrict__ A1, const float* __restrict__ wgt,
    const float* __restrict__ bs, float* __restrict__ A2) {
  const int c  = blockIdx.x >> 2;
  const int zb = (blockIdx.x & 3) * 6;
  __shared__ __align__(16) float sin_[18*24*36];
  __shared__ float sw[128];
  const int t = threadIdx.x;
  if (t < 125) sw[t] = wgt[c*125 + t];
  const float* xc = A1 + c*VS;
  for (int i = t; i < 18*24*36; i += 256) {
    int px = i % 36;
    int y  = (i / 36) % 24;
    int pz = i / (36*24);
    int xx = px - 6;
    int zz = zb - 6 + pz;
    float v = 0.f;
    if ((unsigned)xx < 24u && (unsigned)zz < 24u) v = xc[zz*HW + y*DS + xx];
    sin_[i] = v;
  }
  __syncthreads();
  const float bias = bs[c];
  for (int g = t; g < 6*24*6; g += 256) {
    int xg = g % 6;
    int y  = (g / 6) % 24;
    int zl = g / 144;   // 0..5
    int x0 = xg * 4;
    float a0=0.f, a1=0.f, a2=0.f, a3=0.f;
    for (int kz = 0; kz < 5; ++kz) {
      int pz = zl + 3*kz;
      for (int ky = 0; ky < 5; ++ky) {
        int yy = y + 3*ky - 6;
        if ((unsigned)yy >= 24u) continue;
        const float* row = &sin_[(pz*24 + yy)*36 + x0];
        float4 r0 = *(const float4*)(row);
        float4 r1 = *(const float4*)(row+4);
        float4 r2 = *(const float4*)(row+8);
        float4 r3 = *(const float4*)(row+12);
        float f[16] = {r0.x,r0.y,r0.z,r0.w, r1.x,r1.y,r1.z,r1.w,
                       r2.x,r2.y,r2.z,r2.w, r3.x,r3.y,r3.z,r3.w};
        const float* wr = &sw[(kz*5+ky)*5];
        #pragma unroll
        for (int kx = 0; kx < 5; ++kx) {
          float w = wr[kx];
          a0 = fmaf(w, f[3*kx],   a0);
          a1 = fmaf(w, f[3*kx+1], a1);
          a2 = fmaf(w, f[3*kx+2], a2);
          a3 = fmaf(w, f[3*kx+3], a3);
        }
      }
    }
    int z = zb + zl;
    int v = (z*DS + y)*DS + x0;
    *(float4*)&A2[c*VS + v] = make_float4(a0+bias, a1+bias, a2+bias, a3+bias);
  }
}

// ---------------------------------------------------------------------------
// K3: transpose A2 [128][V] -> A2t [V][128].
// ---------------------------------------------------------------------------
__global__ __launch_bounds__(256) void transpose_kernel(
    const float* __restrict__ A2, float* __restrict__ A2t) {
  const int vb = (blockIdx.x % 216) * 64;
  const int cb = (blockIdx.x / 216) * 64;
  __shared__ float tile[64][65];
  const int t = threadIdx.x;
  {
    int lv = t % 64, lc4 = t / 64;
    for (int r = 0; r < 16; ++r) {
      int lc = r*4 + lc4;
      tile[lc][lv] = A2[(cb+lc)*VS + vb + lv];
    }
  }
  __syncthreads();
  {
    int lc = t % 64, lv4 = t / 64;
    for (int r = 0; r < 16; ++r) {
      int lv = r*4 + lv4;
      A2t[(vb+lv)*CH + cb + lc] = tile[lc][lv];
    }
  }
}

// ---------------------------------------------------------------------------
// K4: offset conv via bf16 MFMA 16x16x32.  grid = 216 v-tiles x 3 tap-groups.
// Per tap: stage Wl[96 o][128 c] bf16 and Bl[64 v][128 c] bf16 (shifted rows
// of A2t, zero at borders), then 4 k-steps.  16B-granule XOR swizzle (g ^
// row&15) keeps staging writes and b128 frag reads <=2-way (free).
// Wave w: n-tile w (16 v), m-tiles 0..5.  atomicAdd fp32 into OFF.
// LDS 40KB -> 3 blocks/CU.
// ---------------------------------------------------------------------------
__global__ __launch_bounds__(256) void offconv_kernel(
    const float* __restrict__ A2t, const unsigned short* __restrict__ WTh,
    float* __restrict__ OFF) {
  const int vb = (blockIdx.x % 216) * 64;
  const int kg = blockIdx.x / 216;          // 0..2
  __shared__ __align__(16) unsigned short Wl[96*128];  // 24 KB
  __shared__ __align__(16) unsigned short Bl[64*128];  // 16 KB
  const int t    = threadIdx.x;
  const int lane = t & 63, w = t >> 6;
  const int l16  = lane & 15, quad = lane >> 4;
  f32x4 acc[6];
  #pragma unroll
  for (int m = 0; m < 6; ++m) acc[m] = (f32x4){0.f,0.f,0.f,0.f};

  for (int kk = 0; kk < 9; ++kk) {
    const int k  = kg*9 + kk;
    const int dz = k/9 - 1, dy = (k/3)%3 - 1, dx = k%3 - 1;
    const int doff = (dz*DS + dy)*DS + dx;
    __syncthreads();                          // previous tap consumed
    for (int s = t; s < 1536; s += 256) {     // stage W: 96x128 bf16
      int o = s >> 4, cg = s & 15;
      *(uint4*)&Wl[o*128 + ((cg ^ (o & 15)) << 3)] =
          *(const uint4*)&WTh[(k*96 + o)*128 + (cg << 3)];
    }
    {                                         // stage B: shifted rows, cvt bf16
      const int cq = t & 31;
      #pragma unroll
      for (int p = 0; p < 8; ++p) {
        int vl = p*8 + (t >> 5);
        int v  = vb + vl;
        int z = v / HW, y = (v / DS) % DS, xx = v % DS;
        int zz = z + dz, yy = y + dy, xq = xx + dx;
        float4 gv = make_float4(0.f, 0.f, 0.f, 0.f);
        if ((unsigned)zz < 24u && (unsigned)yy < 24u && (unsigned)xq < 24u)
          gv = *(const float4*)&A2t[(v + doff)*CH + (cq << 2)];
        ushort4 pk;
        pk.x = f2bf(gv.x); pk.y = f2bf(gv.y); pk.z = f2bf(gv.z); pk.w = f2bf(gv.w);
        *(ushort4*)&Bl[vl*128 + (((cq >> 1) ^ (vl & 15)) << 3) + ((cq & 1) << 2)] = pk;
      }
    }
    __syncthreads();
    #pragma unroll
    for (int ks = 0; ks < 4; ++ks) {
      int gx = (((ks << 2) + quad) ^ l16) << 3;
      bf16x8 b = *(const bf16x8*)&Bl[((w << 4) + l16)*128 + gx];
      #pragma unroll
      for (int m = 0; m < 6; ++m) {
        bf16x8 a = *(const bf16x8*)&Wl[((m << 4) + l16)*128 + gx];
        acc[m] = __builtin_amdgcn_mfma_f32_16x16x32_bf16(a, b, acc[m], 0, 0, 0);
      }
    }
  }
  #pragma unroll
  for (int m = 0; m < 6; ++m)
    #pragma unroll
    for (int r = 0; r < 4; ++r) {
      int o = (m << 4) + (quad << 2) + r;      // D: row=quad*4+r, col=l16
      if (o < 81)
        atomicAdd(&OFF[o*VS + vb + (w << 4) + l16], acc[m][r]);
    }
}

// ---------------------------------------------------------------------------
// K5: deformable conv via bf16 MFMA.  grid = 216 v-tiles x 9 tap-groups
// (3 taps each).  Per tap: trilinear meta (fp32, from fp32 OFF), gather
// 8-corner samples from A2t -> Bl[64 v][128 c] bf16, stage WDh -> Wl[128 o]
// [128 c] bf16, 4 k-steps x 8 MFMA/wave (wave w: m-tiles 2w,2w+1; n 0..3).
// Same XOR swizzle.  LDS 53.2KB -> 3 blocks/CU.  atomicAdd fp32 into DEF.
// ---------------------------------------------------------------------------
__global__ __launch_bounds__(256) void deform_kernel(
    const float* __restrict__ A2t, const float* __restrict__ OFF,
    const unsigned short* __restrict__ WDh, float* __restrict__ DEF) {
  const int vb = (blockIdx.x % 216) * 64;
  const int kg = blockIdx.x / 216;          // 0..8
  __shared__ __align__(16) unsigned short Wl[128*128]; // 32 KB
  __shared__ __align__(16) unsigned short Bl[64*128];  // 16 KB
  __shared__ float W8[64][8];
  __shared__ int   I8[64][8];
  const int t    = threadIdx.x;
  const int lane = t & 63, w = t >> 6;
  const int l16  = lane & 15, quad = lane >> 4;
  f32x4 acc[2][4];
  #pragma unroll
  for (int i = 0; i < 2; ++i)
    #pragma unroll
    for (int n = 0; n < 4; ++n) acc[i][n] = (f32x4){0.f,0.f,0.f,0.f};

  for (int kk = 0; kk < 3; ++kk) {
    const int k = kg*3 + kk;
    __syncthreads();                          // previous tap consumed
    for (int s = t; s < 2048; s += 256) {     // stage W: 128x128 bf16
      int o = s >> 4, cg = s & 15;
      *(uint4*)&Wl[o*128 + ((cg ^ (o & 15)) << 3)] =
          *(const uint4*)&WDh[(k*CH + o)*CH + (cg << 3)];
    }
    if (t < 64) {                             // trilinear meta (fp32)
      int v = vb + t;
      int z = v / HW, y = (v / DS) % DS, xx = v % DS;
      float cz = (float)(z  + k/9     - 1) + OFF[(3*k + 0)*VS + v];
      float cy = (float)(y  + (k/3)%3 - 1) + OFF[(3*k + 1)*VS + v];
      float cx = (float)(xx + k%3     - 1) + OFF[(3*k + 2)*VS + v];
      float fz = floorf(cz), fy = floorf(cy), fx = floorf(cx);
      int iz = (int)fz, iy = (int)fy, ix = (int)fx;
      float rz = cz - fz, ry = cy - fy, rx = cx - fx;
      #pragma unroll
      for (int corner = 0; corner < 8; ++corner) {
        int ca = corner >> 2, cb = (corner >> 1) & 1, cc = corner & 1;
        int zi = iz + ca, yi = iy + cb, xi = ix + cc;
        float ww = (ca ? rz : 1.f-rz) * (cb ? ry : 1.f-ry) * (cc ? rx : 1.f-rx);
        bool valid = ((unsigned)zi < 24u) && ((unsigned)yi < 24u) && ((unsigned)xi < 24u);
        W8[t][corner] = valid ? ww : 0.f;
        I8[t][corner] = valid ? (zi*DS + yi)*DS + xi : 0;
      }
    }
    __syncthreads();
    {                                         // gather -> Bl bf16
      const int cq = t & 31;
      #pragma unroll
      for (int p = 0; p < 8; ++p) {
        int vl = p*8 + (t >> 5);
        float g0 = 0.f, g1 = 0.f, g2 = 0.f, g3 = 0.f;
        #pragma unroll
        for (int corner = 0; corner < 8; ++corner) {
          float ww = W8[vl][corner];
          const float4 gv = *(const float4*)&A2t[I8[vl][corner]*CH + (cq << 2)];
          g0 = fmaf(ww, gv.x, g0); g1 = fmaf(ww, gv.y, g1);
          g2 = fmaf(ww, gv.z, g2); g3 = fmaf(ww, gv.w, g3);
        }
        ushort4 pk;
        pk.x = f2bf(g0); pk.y = f2bf(g1); pk.z = f2bf(g2); pk.w = f2bf(g3);
        *(ushort4*)&Bl[vl*128 + (((cq >> 1) ^ (vl & 15)) << 3) + ((cq & 1) << 2)] = pk;
      }
    }
    __syncthreads();
    #pragma unroll
    for (int ks = 0; ks < 4; ++ks) {
      int gx = (((ks << 2) + quad) ^ l16) << 3;
      bf16x8 a0 = *(const bf16x8*)&Wl[((w << 5) + l16)*128 + gx];
      bf16x8 a1 = *(const bf16x8*)&Wl[((w << 5) + 16 + l16)*128 + gx];
      #pragma unroll
      for (int n = 0; n < 4; ++n) {
        bf16x8 b = *(const bf16x8*)&Bl[((n << 4) + l16)*128 + gx];
        acc[0][n] = __builtin_amdgcn_mfma_f32_16x16x32_bf16(a0, b, acc[0][n], 0, 0, 0);
        acc[1][n] = __builtin_amdgcn_mfma_f32_16x16x32_bf16(a1, b, acc[1][n], 0, 0, 0);
      }
    }
  }
  #pragma unroll
  for (int i = 0; i < 2; ++i)
    #pragma unroll
    for (int n = 0; n < 4; ++n)
      #pragma unroll
      for (int r = 0; r < 4; ++r) {
        int o = (w << 5) + (i << 4) + (quad << 2) + r;
        int v = vb + (n << 4) + l16;
        atomicAdd(&DEF[o*VS + v], acc[i][n][r]);
      }
}

// ---------------------------------------------------------------------------
// K6: 1x1x1 conv + bias + multiply, 32-v tiles -> 432 blocks (fp32).
// ---------------------------------------------------------------------------
__global__ __launch_bounds__(256) void pw_mul_kernel(
    const float* __restrict__ DEF, const float* __restrict__ W1T,
    const float* __restrict__ b1, const float* __restrict__ x,
    float* __restrict__ out) {
  const int vb = blockIdx.x * 32;
  __shared__ __align__(16) float Wl[64*128];  // 32 KB
  __shared__ __align__(16) float Bl[64*32];   // 8 KB
  const int t  = threadIdx.x;
  const int og = t / 8, vg = t % 8;
  const int o0 = og * 4;
  float acc[4][4];
  #pragma unroll
  for (int i = 0; i < 4; ++i)
    #pragma unroll
    for (int j = 0; j < 4; ++j) acc[i][j] = 0.f;

  for (int chh = 0; chh < 2; ++chh) {
    if (chh) __syncthreads();
    for (int s = t; s < 64*32; s += 256) {
      int cl = s / 32, oq = s % 32;
      *(float4*)&Wl[cl*128 + 4*oq] =
          *(const float4*)&W1T[(chh*64 + cl)*CH + 4*oq];
    }
    for (int s = t; s < 64*8; s += 256) {
      int cl = s / 8, vq = s % 8;
      *(float4*)&Bl[cl*32 + 4*vq] =
          *(const float4*)&DEF[(chh*64 + cl)*VS + vb + 4*vq];
    }
    __syncthreads();
    for (int cl = 0; cl < 64; ++cl) {
      float4 b  = *(const float4*)&Bl[cl*32 + 4*vg];
      float4 w  = *(const float4*)&Wl[cl*128 + o0];
      float wv[4] = {w.x,w.y,w.z,w.w};
      float bv[4] = {b.x,b.y,b.z,b.w};
      #pragma unroll
      for (int i = 0; i < 4; ++i)
        #pragma unroll
        for (int j = 0; j < 4; ++j)
          acc[i][j] = fmaf(wv[i], bv[j], acc[i][j]);
    }
  }
  #pragma unroll
  for (int i = 0; i < 4; ++i) {
    int o = o0 + i;
    float bias = b1[o];
    float4 xs = *(const float4*)&x[o*VS + vb + 4*vg];
    *(float4*)&out[o*VS + vb + 4*vg] =
        make_float4(xs.x*(acc[i][0]+bias), xs.y*(acc[i][1]+bias),
                    xs.z*(acc[i][2]+bias), xs.w*(acc[i][3]+bias));
  }
}

// ---------------------------------------------------------------------------
extern "C" void kernel_launch(void* const* d_in, const int* in_sizes, int n_in,
                              void* d_out, int out_size, void* d_ws, size_t ws_size,
                              hipStream_t stream) {
  (void)in_sizes; (void)n_in; (void)out_size; (void)ws_size;
  const float* x     = (const float*)d_in[0];
  const float* w0    = (const float*)d_in[1];
  const float* b0    = (const float*)d_in[2];
  const float* wsw   = (const float*)d_in[3];
  const float* bs    = (const float*)d_in[4];
  const float* w_off = (const float*)d_in[5];
  const float* b_off = (const float*)d_in[6];
  const float* w_def = (const float*)d_in[7];
  const float* b_def = (const float*)d_in[8];
  const float* w1    = (const float*)d_in[9];
  const float* b1    = (const float*)d_in[10];
  float* out = (float*)d_out;

  float* wsf = (float*)d_ws;
  float* A1  = wsf;                       // 1769472 floats (reused as OFF)
  float* A2  = A1  + 1769472;
  float* A2t = A2  + 1769472;
  float* DEF = A2t + 1769472;
  unsigned short* WTh = (unsigned short*)(DEF + 1769472);  // 331776 bf16
  unsigned short* WDh = WTh + 331776;                      // 442368 bf16
  float* W1T = (float*)(WDh + 442368);                     // 16384 fp32
  float* OFF = A1;                        // A1 dead after dwdil

  prep_weights    <<<1024,  256, 0, stream>>>(w_off, w_def, w1, WTh, WDh, W1T);
  dw5_kernel      <<<256,   256, 0, stream>>>(x, w0, b0, A1);
  dwdil_kernel    <<<512,   256, 0, stream>>>(A1, wsw, bs, A2);
  init_bias       <<<11286, 256, 0, stream>>>(b_off, b_def, OFF, DEF);
  transpose_kernel<<<432,   256, 0, stream>>>(A2, A2t);
  offconv_kernel  <<<648,   256, 0, stream>>>(A2t, WTh, OFF);
  deform_kernel   <<<1944,  256, 0, stream>>>(A2t, OFF, WDh, DEF);
  pw_mul_kernel   <<<432,   256, 0, stream>>>(DEF, W1T, b1, x, out);
}

// Round 4
// 321.198 us; speedup vs baseline: 2.9834x; 1.1755x over previous
//
#include <hip/hip_runtime.h>

#define CH 128
#define DS 24
#define HW (DS*DS)      // 576
#define VS (DS*DS*DS)   // 13824

typedef __attribute__((ext_vector_type(8))) short    bf16x8;
typedef __attribute__((ext_vector_type(4))) float    f32x4;
typedef _Float16 h4 __attribute__((ext_vector_type(4)));

__device__ __forceinline__ unsigned short f2bf(float f) {
  union { float f; unsigned u; } v; v.f = f;
  unsigned r = v.u + 0x7FFFu + ((v.u >> 16) & 1u);   // RNE
  return (unsigned short)(r >> 16);
}
__device__ __forceinline__ float bf2f(unsigned short s) {
  union { unsigned u; float f; } v; v.u = ((unsigned)s) << 16;
  return v.f;
}

// ---------------------------------------------------------------------------
// K0: weight prep.  WTh[k][96 o][128 c] bf16 (o 81..95 zero), WDh[k][128 o]
// [128 c] bf16, W1T[c][128 o] fp32.
// ---------------------------------------------------------------------------
__global__ __launch_bounds__(256) void prep_weights(
    const float* __restrict__ w_off, const float* __restrict__ w_def,
    const float* __restrict__ w1,
    unsigned short* __restrict__ WTh, unsigned short* __restrict__ WDh,
    float* __restrict__ W1T) {
  const int n1 = 27*96*128, n2 = 27*128*128, n3 = 128*128;
  const int ntot = n1 + n2 + n3;
  for (int i = blockIdx.x*256 + threadIdx.x; i < ntot; i += gridDim.x*256) {
    if (i < n1) {
      int c = i & 127, o = (i >> 7) % 96, k = i / (96*128);
      WTh[i] = (o < 81) ? f2bf(w_off[(o*128 + c)*27 + k]) : (unsigned short)0;
    } else if (i < n1 + n2) {
      int j = i - n1;
      int c = j & 127, o = (j >> 7) & 127, k = j >> 14;
      WDh[j] = f2bf(w_def[(o*128 + c)*27 + k]);
    } else {
      int j = i - n1 - n2;
      int o = j & 127, c = j >> 7;
      W1T[j] = w1[o*128 + c];
    }
  }
}

// ---------------------------------------------------------------------------
// K1: depthwise 5x5x5, pad=2.  Block per (channel, z-quarter of 6).
// LDS slab [10 z][24 y][36 x], 35 KB -> 4 blocks/CU, grid 512.
// ---------------------------------------------------------------------------
__global__ __launch_bounds__(256) void dw5_kernel(
    const float* __restrict__ x, const float* __restrict__ w0,
    const float* __restrict__ b0, float* __restrict__ A1) {
  const int c  = blockIdx.x >> 2;
  const int zb = (blockIdx.x & 3) * 6;
  __shared__ __align__(16) float sin_[10*24*36];
  __shared__ float sw[128];
  const int t = threadIdx.x;
  if (t < 125) sw[t] = w0[c*125 + t];
  const float* xc = x + c*VS;
  for (int i = t; i < 10*24*36; i += 256) {
    int px = i % 36;
    int y  = (i / 36) % 24;
    int pz = i / (36*24);
    int xx = px - 2;
    int zz = zb - 2 + pz;
    float v = 0.f;
    if ((unsigned)xx < 24u && (unsigned)zz < 24u) v = xc[zz*HW + y*DS + xx];
    sin_[i] = v;
  }
  __syncthreads();
  const float bias = b0[c];
  for (int g = t; g < 6*24*6; g += 256) {
    int xg = g % 6;
    int y  = (g / 6) % 24;
    int zl = g / 144;    // 0..5
    int x0 = xg * 4;
    float a0=0.f, a1=0.f, a2=0.f, a3=0.f;
    for (int kz = 0; kz < 5; ++kz) {
      int pz = zl + kz;
      for (int ky = 0; ky < 5; ++ky) {
        int yy = y + ky - 2;
        if ((unsigned)yy >= 24u) continue;
        const float* row = &sin_[(pz*24 + yy)*36 + x0];
        float4 r0 = *(const float4*)(row);
        float4 r1 = *(const float4*)(row+4);
        float4 r2 = *(const float4*)(row+8);
        float f[12] = {r0.x,r0.y,r0.z,r0.w, r1.x,r1.y,r1.z,r1.w,
                       r2.x,r2.y,r2.z,r2.w};
        const float* wr = &sw[(kz*5+ky)*5];
        #pragma unroll
        for (int kx = 0; kx < 5; ++kx) {
          float w = wr[kx];
          a0 = fmaf(w, f[kx],   a0);
          a1 = fmaf(w, f[kx+1], a1);
          a2 = fmaf(w, f[kx+2], a2);
          a3 = fmaf(w, f[kx+3], a3);
        }
      }
    }
    int z = zb + zl;
    int v = (z*DS + y)*DS + x0;
    *(float4*)&A1[c*VS + v] = make_float4(a0+bias, a1+bias, a2+bias, a3+bias);
  }
}

// ---------------------------------------------------------------------------
// K2: depthwise 5x5x5, dilation=3, pad=6.  Block per (channel, z-quarter).
// ---------------------------------------------------------------------------
__global__ __launch_bounds__(256) void dwdil_kernel(
    const float* __restrict__ A1, const float* __restrict__ wgt,
    const float* __restrict__ bs, float* __restrict__ A2) {
  const int c  = blockIdx.x >> 2;
  const int zb = (blockIdx.x & 3) * 6;
  __shared__ __align__(16) float sin_[18*24*36];
  __shared__ float sw[128];
  const int t = threadIdx.x;
  if (t < 125) sw[t] = wgt[c*125 + t];
  const float* xc = A1 + c*VS;
  for (int i = t; i < 18*24*36; i += 256) {
    int px = i % 36;
    int y  = (i / 36) % 24;
    int pz = i / (36*24);
    int xx = px - 6;
    int zz = zb - 6 + pz;
    float v = 0.f;
    if ((unsigned)xx < 24u && (unsigned)zz < 24u) v = xc[zz*HW + y*DS + xx];
    sin_[i] = v;
  }
  __syncthreads();
  const float bias = bs[c];
  for (int g = t; g < 6*24*6; g += 256) {
    int xg = g % 6;
    int y  = (g / 6) % 24;
    int zl = g / 144;   // 0..5
    int x0 = xg * 4;
    float a0=0.f, a1=0.f, a2=0.f, a3=0.f;
    for (int kz = 0; kz < 5; ++kz) {
      int pz = zl + 3*kz;
      for (int ky = 0; ky < 5; ++ky) {
        int yy = y + 3*ky - 6;
        if ((unsigned)yy >= 24u) continue;
        const float* row = &sin_[(pz*24 + yy)*36 + x0];
        float4 r0 = *(const float4*)(row);
        float4 r1 = *(const float4*)(row+4);
        float4 r2 = *(const float4*)(row+8);
        float4 r3 = *(const float4*)(row+12);
        float f[16] = {r0.x,r0.y,r0.z,r0.w, r1.x,r1.y,r1.z,r1.w,
                       r2.x,r2.y,r2.z,r2.w, r3.x,r3.y,r3.z,r3.w};
        const float* wr = &sw[(kz*5+ky)*5];
        #pragma unroll
        for (int kx = 0; kx < 5; ++kx) {
          float w = wr[kx];
          a0 = fmaf(w, f[3*kx],   a0);
          a1 = fmaf(w, f[3*kx+1], a1);
          a2 = fmaf(w, f[3*kx+2], a2);
          a3 = fmaf(w, f[3*kx+3], a3);
        }
      }
    }
    int z = zb + zl;
    int v = (z*DS + y)*DS + x0;
    *(float4*)&A2[c*VS + v] = make_float4(a0+bias, a1+bias, a2+bias, a3+bias);
  }
}

// ---------------------------------------------------------------------------
// K3: transpose A2 [128][V] fp32 -> A2tb [V][128] bf16.
// ---------------------------------------------------------------------------
__global__ __launch_bounds__(256) void transpose_kernel(
    const float* __restrict__ A2, unsigned short* __restrict__ A2tb) {
  const int vb = (blockIdx.x % 216) * 64;
  const int cb = (blockIdx.x / 216) * 64;
  __shared__ float tile[64][65];
  const int t = threadIdx.x;
  {
    int lv = t % 64, lc4 = t / 64;
    for (int r = 0; r < 16; ++r) {
      int lc = r*4 + lc4;
      tile[lc][lv] = A2[(cb+lc)*VS + vb + lv];
    }
  }
  __syncthreads();
  {
    int lc = t % 64, lv4 = t / 64;
    for (int r = 0; r < 16; ++r) {
      int lv = r*4 + lv4;
      A2tb[(vb+lv)*CH + cb + lc] = f2bf(tile[lc][lv]);
    }
  }
}

// ---------------------------------------------------------------------------
// K4: offset conv via bf16 MFMA 16x16x32.  grid = 216 v-tiles x 3 tap-groups
// (9 taps, register-accumulated).  Writes fp16 partial OFFp[kg][81][V] with
// plain stores (NO atomics).  B staged directly from bf16 A2tb (no cvt).
// ---------------------------------------------------------------------------
__global__ __launch_bounds__(256) void offconv_kernel(
    const unsigned short* __restrict__ A2tb, const unsigned short* __restrict__ WTh,
    _Float16* __restrict__ OFFp) {
  const int vb = (blockIdx.x % 216) * 64;
  const int kg = blockIdx.x / 216;          // 0..2
  __shared__ __align__(16) unsigned short Wl[96*128];  // 24 KB
  __shared__ __align__(16) unsigned short Bl[64*128];  // 16 KB
  const int t    = threadIdx.x;
  const int lane = t & 63, w = t >> 6;
  const int l16  = lane & 15, quad = lane >> 4;
  f32x4 acc[6];
  #pragma unroll
  for (int m = 0; m < 6; ++m) acc[m] = (f32x4){0.f,0.f,0.f,0.f};

  for (int kk = 0; kk < 9; ++kk) {
    const int k  = kg*9 + kk;
    const int dz = k/9 - 1, dy = (k/3)%3 - 1, dx = k%3 - 1;
    const int doff = (dz*DS + dy)*DS + dx;
    __syncthreads();                          // previous tap consumed
    for (int s = t; s < 1536; s += 256) {     // stage W: 96x128 bf16
      int o = s >> 4, cg = s & 15;
      *(uint4*)&Wl[o*128 + ((cg ^ (o & 15)) << 3)] =
          *(const uint4*)&WTh[(k*96 + o)*128 + (cg << 3)];
    }
    {                                         // stage B: shifted bf16 rows
      const int cq = t & 31;
      #pragma unroll
      for (int p = 0; p < 8; ++p) {
        int vl = p*8 + (t >> 5);
        int v  = vb + vl;
        int z = v / HW, y = (v / DS) % DS, xx = v % DS;
        int zz = z + dz, yy = y + dy, xq = xx + dx;
        ushort4 pk = make_ushort4(0,0,0,0);
        if ((unsigned)zz < 24u && (unsigned)yy < 24u && (unsigned)xq < 24u)
          pk = *(const ushort4*)&A2tb[(v + doff)*CH + (cq << 2)];
        *(ushort4*)&Bl[vl*128 + (((cq >> 1) ^ (vl & 15)) << 3) + ((cq & 1) << 2)] = pk;
      }
    }
    __syncthreads();
    #pragma unroll
    for (int ks = 0; ks < 4; ++ks) {
      int gx = (((ks << 2) + quad) ^ l16) << 3;
      bf16x8 b = *(const bf16x8*)&Bl[((w << 4) + l16)*128 + gx];
      #pragma unroll
      for (int m = 0; m < 6; ++m) {
        bf16x8 a = *(const bf16x8*)&Wl[((m << 4) + l16)*128 + gx];
        acc[m] = __builtin_amdgcn_mfma_f32_16x16x32_bf16(a, b, acc[m], 0, 0, 0);
      }
    }
  }
  #pragma unroll
  for (int m = 0; m < 6; ++m)
    #pragma unroll
    for (int r = 0; r < 4; ++r) {
      int o = (m << 4) + (quad << 2) + r;      // D: row=quad*4+r, col=l16
      if (o < 81)
        OFFp[(kg*81 + o)*VS + vb + (w << 4) + l16] = (_Float16)acc[m][r];
    }
}

// ---------------------------------------------------------------------------
// K5: deformable conv via bf16 MFMA.  grid = 216 v-tiles x 3 tap-groups
// (9 taps, register-accumulated).  Meta sums 3 fp16 OFF partials + b_off.
// Gather reads bf16 A2tb (half the L2 bytes).  Writes fp16 partial
// DEFp[kg][128][V] with plain stores (NO atomics).
// ---------------------------------------------------------------------------
__global__ __launch_bounds__(256) void deform_kernel(
    const unsigned short* __restrict__ A2tb, const _Float16* __restrict__ OFFp,
    const float* __restrict__ b_off, const unsigned short* __restrict__ WDh,
    _Float16* __restrict__ D0, _Float16* __restrict__ D1,
    _Float16* __restrict__ D2) {
  const int vb = (blockIdx.x % 216) * 64;
  const int kg = blockIdx.x / 216;          // 0..2
  _Float16* DP = (kg == 0) ? D0 : (kg == 1) ? D1 : D2;
  __shared__ __align__(16) unsigned short Wl[128*128]; // 32 KB
  __shared__ __align__(16) unsigned short Bl[64*128];  // 16 KB
  __shared__ float W8[64][8];
  __shared__ int   I8[64][8];
  const int t    = threadIdx.x;
  const int lane = t & 63, w = t >> 6;
  const int l16  = lane & 15, quad = lane >> 4;
  f32x4 acc[2][4];
  #pragma unroll
  for (int i = 0; i < 2; ++i)
    #pragma unroll
    for (int n = 0; n < 4; ++n) acc[i][n] = (f32x4){0.f,0.f,0.f,0.f};

  for (int kk = 0; kk < 9; ++kk) {
    const int k = kg*9 + kk;
    __syncthreads();                          // previous tap consumed
    for (int s = t; s < 2048; s += 256) {     // stage W: 128x128 bf16
      int o = s >> 4, cg = s & 15;
      *(uint4*)&Wl[o*128 + ((cg ^ (o & 15)) << 3)] =
          *(const uint4*)&WDh[(k*CH + o)*CH + (cg << 3)];
    }
    if (t < 64) {                             // trilinear meta (fp32)
      int v = vb + t;
      int z = v / HW, y = (v / DS) % DS, xx = v % DS;
      float po[3];
      #pragma unroll
      for (int a = 0; a < 3; ++a) {
        int row = 3*k + a;
        po[a] = (float)OFFp[row*VS + v] + (float)OFFp[(81 + row)*VS + v]
              + (float)OFFp[(162 + row)*VS + v] + b_off[row];
      }
      float cz = (float)(z  + k/9     - 1) + po[0];
      float cy = (float)(y  + (k/3)%3 - 1) + po[1];
      float cx = (float)(xx + k%3     - 1) + po[2];
      float fz = floorf(cz), fy = floorf(cy), fx = floorf(cx);
      int iz = (int)fz, iy = (int)fy, ix = (int)fx;
      float rz = cz - fz, ry = cy - fy, rx = cx - fx;
      #pragma unroll
      for (int corner = 0; corner < 8; ++corner) {
        int ca = corner >> 2, cb = (corner >> 1) & 1, cc = corner & 1;
        int zi = iz + ca, yi = iy + cb, xi = ix + cc;
        float ww = (ca ? rz : 1.f-rz) * (cb ? ry : 1.f-ry) * (cc ? rx : 1.f-rx);
        bool valid = ((unsigned)zi < 24u) && ((unsigned)yi < 24u) && ((unsigned)xi < 24u);
        W8[t][corner] = valid ? ww : 0.f;
        I8[t][corner] = valid ? (zi*DS + yi)*DS + xi : 0;
      }
    }
    __syncthreads();
    {                                         // gather bf16 -> weighted -> Bl
      const int cq = t & 31;
      #pragma unroll
      for (int p = 0; p < 8; ++p) {
        int vl = p*8 + (t >> 5);
        float g0 = 0.f, g1 = 0.f, g2 = 0.f, g3 = 0.f;
        #pragma unroll
        for (int corner = 0; corner < 8; ++corner) {
          float ww = W8[vl][corner];
          const ushort4 gv = *(const ushort4*)&A2tb[I8[vl][corner]*CH + (cq << 2)];
          g0 = fmaf(ww, bf2f(gv.x), g0); g1 = fmaf(ww, bf2f(gv.y), g1);
          g2 = fmaf(ww, bf2f(gv.z), g2); g3 = fmaf(ww, bf2f(gv.w), g3);
        }
        ushort4 pk;
        pk.x = f2bf(g0); pk.y = f2bf(g1); pk.z = f2bf(g2); pk.w = f2bf(g3);
        *(ushort4*)&Bl[vl*128 + (((cq >> 1) ^ (vl & 15)) << 3) + ((cq & 1) << 2)] = pk;
      }
    }
    __syncthreads();
    #pragma unroll
    for (int ks = 0; ks < 4; ++ks) {
      int gx = (((ks << 2) + quad) ^ l16) << 3;
      bf16x8 a0 = *(const bf16x8*)&Wl[((w << 5) + l16)*128 + gx];
      bf16x8 a1 = *(const bf16x8*)&Wl[((w << 5) + 16 + l16)*128 + gx];
      #pragma unroll
      for (int n = 0; n < 4; ++n) {
        bf16x8 b = *(const bf16x8*)&Bl[((n << 4) + l16)*128 + gx];
        acc[0][n] = __builtin_amdgcn_mfma_f32_16x16x32_bf16(a0, b, acc[0][n], 0, 0, 0);
        acc[1][n] = __builtin_amdgcn_mfma_f32_16x16x32_bf16(a1, b, acc[1][n], 0, 0, 0);
      }
    }
  }
  #pragma unroll
  for (int i = 0; i < 2; ++i)
    #pragma unroll
    for (int n = 0; n < 4; ++n)
      #pragma unroll
      for (int r = 0; r < 4; ++r) {
        int o = (w << 5) + (i << 4) + (quad << 2) + r;
        int v = vb + (n << 4) + l16;
        DP[o*VS + v] = (_Float16)acc[i][n][r];
      }
}

// ---------------------------------------------------------------------------
// K6: sum 3 fp16 DEF partials + b_def, 1x1x1 conv, + b1, multiply by x.
// ---------------------------------------------------------------------------
__global__ __launch_bounds__(256) void pw_mul_kernel(
    const _Float16* __restrict__ D0, const _Float16* __restrict__ D1,
    const _Float16* __restrict__ D2, const float* __restrict__ b_def,
    const float* __restrict__ W1T, const float* __restrict__ b1,
    const float* __restrict__ x, float* __restrict__ out) {
  const int vb = blockIdx.x * 32;
  __shared__ __align__(16) float Wl[64*128];  // 32 KB
  __shared__ __align__(16) float Bl[64*32];   // 8 KB
  const int t  = threadIdx.x;
  const int og = t / 8, vg = t % 8;
  const int o0 = og * 4;
  float acc[4][4];
  #pragma unroll
  for (int i = 0; i < 4; ++i)
    #pragma unroll
    for (int j = 0; j < 4; ++j) acc[i][j] = 0.f;

  for (int chh = 0; chh < 2; ++chh) {
    if (chh) __syncthreads();
    for (int s = t; s < 64*32; s += 256) {
      int cl = s / 32, oq = s % 32;
      *(float4*)&Wl[cl*128 + 4*oq] =
          *(const float4*)&W1T[(chh*64 + cl)*CH + 4*oq];
    }
    for (int s = t; s < 64*8; s += 256) {
      int cl = s / 8, vq = s % 8;
      int c  = chh*64 + cl;
      int idx = c*VS + vb + 4*vq;
      h4 a0 = *(const h4*)&D0[idx];
      h4 a1 = *(const h4*)&D1[idx];
      h4 a2 = *(const h4*)&D2[idx];
      float bd = b_def[c];
      *(float4*)&Bl[cl*32 + 4*vq] = make_float4(
          (float)a0.x + (float)a1.x + (float)a2.x + bd,
          (float)a0.y + (float)a1.y + (float)a2.y + bd,
          (float)a0.z + (float)a1.z + (float)a2.z + bd,
          (float)a0.w + (float)a1.w + (float)a2.w + bd);
    }
    __syncthreads();
    for (int cl = 0; cl < 64; ++cl) {
      float4 b  = *(const float4*)&Bl[cl*32 + 4*vg];
      float4 w  = *(const float4*)&Wl[cl*128 + o0];
      float wv[4] = {w.x,w.y,w.z,w.w};
      float bv[4] = {b.x,b.y,b.z,b.w};
      #pragma unroll
      for (int i = 0; i < 4; ++i)
        #pragma unroll
        for (int j = 0; j < 4; ++j)
          acc[i][j] = fmaf(wv[i], bv[j], acc[i][j]);
    }
  }
  #pragma unroll
  for (int i = 0; i < 4; ++i) {
    int o = o0 + i;
    float bias = b1[o];
    float4 xs = *(const float4*)&x[o*VS + vb + 4*vg];
    *(float4*)&out[o*VS + vb + 4*vg] =
        make_float4(xs.x*(acc[i][0]+bias), xs.y*(acc[i][1]+bias),
                    xs.z*(acc[i][2]+bias), xs.w*(acc[i][3]+bias));
  }
}

// ---------------------------------------------------------------------------
// Workspace layout (floats; total 5,711,872 f = 22.9 MB, < proven 29.9 MB):
//   [0        , 1769472)  BUF_A: A1 (dw5 out) -> later DEFp[0],DEFp[1] fp16
//   [1769472  , 3538944)  BUF_B: A2 (dwdil out) -> later OFFp[3][81][V] fp16
//   [3538944  , 4423680)  A2tb: [V][128] bf16
//   [4423680  , 5308416)  DEFp[2] fp16
//   [5308416  , ...)      WTh (165888 f) | WDh (221184 f) | W1T (16384 f)
// ---------------------------------------------------------------------------
extern "C" void kernel_launch(void* const* d_in, const int* in_sizes, int n_in,
                              void* d_out, int out_size, void* d_ws, size_t ws_size,
                              hipStream_t stream) {
  (void)in_sizes; (void)n_in; (void)out_size; (void)ws_size;
  const float* x     = (const float*)d_in[0];
  const float* w0    = (const float*)d_in[1];
  const float* b0    = (const float*)d_in[2];
  const float* wsw   = (const float*)d_in[3];
  const float* bs    = (const float*)d_in[4];
  const float* w_off = (const float*)d_in[5];
  const float* b_off = (const float*)d_in[6];
  const float* w_def = (const float*)d_in[7];
  const float* b_def = (const float*)d_in[8];
  const float* w1    = (const float*)d_in[9];
  const float* b1    = (const float*)d_in[10];
  float* out = (float*)d_out;

  float* wsf = (float*)d_ws;
  float*          A1   = wsf;                                  // BUF_A
  float*          A2   = wsf + 1769472;                        // BUF_B
  unsigned short* A2tb = (unsigned short*)(wsf + 3538944);
  _Float16*       OFFp = (_Float16*)A2;                        // after transpose
  _Float16*       D0   = (_Float16*)A1;                        // after dwdil
  _Float16*       D1   = D0 + 1769472;                         // 128*VS halfs
  _Float16*       D2   = (_Float16*)(wsf + 4423680);
  unsigned short* WTh  = (unsigned short*)(wsf + 5308416);     // 331776 ush
  unsigned short* WDh  = WTh + 331776;                         // 442368 ush
  float*          W1T  = (float*)(WDh + 442368);               // 16384 f

  prep_weights    <<<1024, 256, 0, stream>>>(w_off, w_def, w1, WTh, WDh, W1T);
  dw5_kernel      <<<512,  256, 0, stream>>>(x, w0, b0, A1);
  dwdil_kernel    <<<512,  256, 0, stream>>>(A1, wsw, bs, A2);
  transpose_kernel<<<432,  256, 0, stream>>>(A2, A2tb);
  offconv_kernel  <<<648,  256, 0, stream>>>(A2tb, WTh, OFFp);
  deform_kernel   <<<648,  256, 0, stream>>>(A2tb, OFFp, b_off, WDh, D0, D1, D2);
  pw_mul_kernel   <<<432,  256, 0, stream>>>(D0, D1, D2, b_def, W1T, b1, x, out);
}

// Round 5
// 318.794 us; speedup vs baseline: 3.0059x; 1.0075x over previous
//
#include <hip/hip_runtime.h>

#define CH 128
#define DS 24
#define HW (DS*DS)      // 576
#define VS (DS*DS*DS)   // 13824

typedef _Float16 f16x8 __attribute__((ext_vector_type(8)));
typedef _Float16 half2v __attribute__((ext_vector_type(2)));
typedef __attribute__((ext_vector_type(4))) float f32x4;
typedef _Float16 h4 __attribute__((ext_vector_type(4)));

__device__ __forceinline__ half2v u2h(unsigned u) {
  union { unsigned u; half2v h; } v; v.u = u; return v.h;
}
__device__ __forceinline__ unsigned h2u(half2v h) {
  union { unsigned u; half2v h; } v; v.h = h; return v.u;
}

// ---------------------------------------------------------------------------
// K0: weight prep, coalesced via LDS transpose.
//  blocks [0,96):    WTh[k][96 o][128 c] fp16, row o=b (o>=81 -> zeros)
//  blocks [96,224):  WDh[k][128 o][128 c] fp16, row o=b-96
//  blocks [224,228): W1T[c][128 o] fp32, 64x64 tiles
// ---------------------------------------------------------------------------
__global__ __launch_bounds__(256) void prep_weights(
    const float* __restrict__ w_off, const float* __restrict__ w_def,
    const float* __restrict__ w1,
    _Float16* __restrict__ WTh, _Float16* __restrict__ WDh,
    float* __restrict__ W1T) {
  __shared__ float sbuf[4224];
  const int b = blockIdx.x, t = threadIdx.x;
  if (b < 96) {
    const int o = b;
    if (o < 81) {
      for (int s = t; s < 3456; s += 256) sbuf[s] = w_off[o*3456 + s];
      __syncthreads();
      for (int s = t; s < 3456; s += 256) {
        int k = s >> 7, c = s & 127;
        WTh[(k*96 + o)*128 + c] = (_Float16)sbuf[c*27 + k];
      }
    } else {
      for (int s = t; s < 3456; s += 256) {
        int k = s >> 7, c = s & 127;
        WTh[(k*96 + o)*128 + c] = (_Float16)0.f;
      }
    }
  } else if (b < 224) {
    const int o = b - 96;
    for (int s = t; s < 3456; s += 256) sbuf[s] = w_def[o*3456 + s];
    __syncthreads();
    for (int s = t; s < 3456; s += 256) {
      int k = s >> 7, c = s & 127;
      WDh[(k*128 + o)*128 + c] = (_Float16)sbuf[c*27 + k];
    }
  } else {
    const int tb = b - 224;
    const int ob = (tb >> 1) * 64, cb = (tb & 1) * 64;
    {
      int j = t & 63, i4 = t >> 6;
      for (int r = 0; r < 16; ++r) {
        int i = r*4 + i4;
        sbuf[i*66 + j] = w1[(ob + i)*128 + cb + j];
      }
    }
    __syncthreads();
    {
      int i = t & 63, j4 = t >> 6;
      for (int r = 0; r < 16; ++r) {
        int j = r*4 + j4;
        W1T[(cb + j)*128 + ob + i] = sbuf[i*66 + j];
      }
    }
  }
}

// ---------------------------------------------------------------------------
// K1: depthwise 5x5x5, pad=2.  Block per (channel, z-quarter of 6).
// ---------------------------------------------------------------------------
__global__ __launch_bounds__(256) void dw5_kernel(
    const float* __restrict__ x, const float* __restrict__ w0,
    const float* __restrict__ b0, float* __restrict__ A1) {
  const int c  = blockIdx.x >> 2;
  const int zb = (blockIdx.x & 3) * 6;
  __shared__ __align__(16) float sin_[10*24*36];
  __shared__ float sw[128];
  const int t = threadIdx.x;
  if (t < 125) sw[t] = w0[c*125 + t];
  const float* xc = x + c*VS;
  for (int i = t; i < 10*24*36; i += 256) {
    int px = i % 36;
    int y  = (i / 36) % 24;
    int pz = i / (36*24);
    int xx = px - 2;
    int zz = zb - 2 + pz;
    float v = 0.f;
    if ((unsigned)xx < 24u && (unsigned)zz < 24u) v = xc[zz*HW + y*DS + xx];
    sin_[i] = v;
  }
  __syncthreads();
  const float bias = b0[c];
  for (int g = t; g < 6*24*6; g += 256) {
    int xg = g % 6;
    int y  = (g / 6) % 24;
    int zl = g / 144;
    int x0 = xg * 4;
    float a0=0.f, a1=0.f, a2=0.f, a3=0.f;
    for (int kz = 0; kz < 5; ++kz) {
      int pz = zl + kz;
      for (int ky = 0; ky < 5; ++ky) {
        int yy = y + ky - 2;
        if ((unsigned)yy >= 24u) continue;
        const float* row = &sin_[(pz*24 + yy)*36 + x0];
        float4 r0 = *(const float4*)(row);
        float4 r1 = *(const float4*)(row+4);
        float4 r2 = *(const float4*)(row+8);
        float f[12] = {r0.x,r0.y,r0.z,r0.w, r1.x,r1.y,r1.z,r1.w,
                       r2.x,r2.y,r2.z,r2.w};
        const float* wr = &sw[(kz*5+ky)*5];
        #pragma unroll
        for (int kx = 0; kx < 5; ++kx) {
          float w = wr[kx];
          a0 = fmaf(w, f[kx],   a0);
          a1 = fmaf(w, f[kx+1], a1);
          a2 = fmaf(w, f[kx+2], a2);
          a3 = fmaf(w, f[kx+3], a3);
        }
      }
    }
    int z = zb + zl;
    int v = (z*DS + y)*DS + x0;
    *(float4*)&A1[c*VS + v] = make_float4(a0+bias, a1+bias, a2+bias, a3+bias);
  }
}

// ---------------------------------------------------------------------------
// K2: depthwise 5x5x5 dil=3 pad=6 + fused transpose: writes A2th[v][128 c]
// fp16 directly (scattered 2B stores; saves the standalone transpose kernel).
// ---------------------------------------------------------------------------
__global__ __launch_bounds__(256) void dwdil_kernel(
    const float* __restrict__ A1, const float* __restrict__ wgt,
    const float* __restrict__ bs, _Float16* __restrict__ A2th) {
  const int c  = blockIdx.x >> 2;
  const int zb = (blockIdx.x & 3) * 6;
  __shared__ __align__(16) float sin_[18*24*36];
  __shared__ float sw[128];
  const int t = threadIdx.x;
  if (t < 125) sw[t] = wgt[c*125 + t];
  const float* xc = A1 + c*VS;
  for (int i = t; i < 18*24*36; i += 256) {
    int px = i % 36;
    int y  = (i / 36) % 24;
    int pz = i / (36*24);
    int xx = px - 6;
    int zz = zb - 6 + pz;
    float v = 0.f;
    if ((unsigned)xx < 24u && (unsigned)zz < 24u) v = xc[zz*HW + y*DS + xx];
    sin_[i] = v;
  }
  __syncthreads();
  const float bias = bs[c];
  for (int g = t; g < 6*24*6; g += 256) {
    int xg = g % 6;
    int y  = (g / 6) % 24;
    int zl = g / 144;   // 0..5
    int x0 = xg * 4;
    float a0=0.f, a1=0.f, a2=0.f, a3=0.f;
    for (int kz = 0; kz < 5; ++kz) {
      int pz = zl + 3*kz;
      for (int ky = 0; ky < 5; ++ky) {
        int yy = y + 3*ky - 6;
        if ((unsigned)yy >= 24u) continue;
        const float* row = &sin_[(pz*24 + yy)*36 + x0];
        float4 r0 = *(const float4*)(row);
        float4 r1 = *(const float4*)(row+4);
        float4 r2 = *(const float4*)(row+8);
        float4 r3 = *(const float4*)(row+12);
        float f[16] = {r0.x,r0.y,r0.z,r0.w, r1.x,r1.y,r1.z,r1.w,
                       r2.x,r2.y,r2.z,r2.w, r3.x,r3.y,r3.z,r3.w};
        const float* wr = &sw[(kz*5+ky)*5];
        #pragma unroll
        for (int kx = 0; kx < 5; ++kx) {
          float w = wr[kx];
          a0 = fmaf(w, f[3*kx],   a0);
          a1 = fmaf(w, f[3*kx+1], a1);
          a2 = fmaf(w, f[3*kx+2], a2);
          a3 = fmaf(w, f[3*kx+3], a3);
        }
      }
    }
    int z = zb + zl;
    int v = (z*DS + y)*DS + x0;
    A2th[(v+0)*CH + c] = (_Float16)(a0+bias);
    A2th[(v+1)*CH + c] = (_Float16)(a1+bias);
    A2th[(v+2)*CH + c] = (_Float16)(a2+bias);
    A2th[(v+3)*CH + c] = (_Float16)(a3+bias);
  }
}

// ---------------------------------------------------------------------------
// K4: offset conv via f16 MFMA 16x16x32.  grid = 216 v-tiles x 3 tap-groups
// (9 taps register-accumulated).  fp16 partials OFFp[kg][81][V], no atomics.
// ---------------------------------------------------------------------------
__global__ __launch_bounds__(256) void offconv_kernel(
    const _Float16* __restrict__ A2th, const _Float16* __restrict__ WTh,
    _Float16* __restrict__ OFFp) {
  const int vb = (blockIdx.x % 216) * 64;
  const int kg = blockIdx.x / 216;          // 0..2
  __shared__ __align__(16) _Float16 Wl[96*128];  // 24 KB
  __shared__ __align__(16) _Float16 Bl[64*128];  // 16 KB
  const int t    = threadIdx.x;
  const int lane = t & 63, w = t >> 6;
  const int l16  = lane & 15, quad = lane >> 4;
  f32x4 acc[6];
  #pragma unroll
  for (int m = 0; m < 6; ++m) acc[m] = (f32x4){0.f,0.f,0.f,0.f};

  for (int kk = 0; kk < 9; ++kk) {
    const int k  = kg*9 + kk;
    const int dz = k/9 - 1, dy = (k/3)%3 - 1, dx = k%3 - 1;
    const int doff = (dz*DS + dy)*DS + dx;
    __syncthreads();                          // previous tap consumed
    for (int s = t; s < 1536; s += 256) {     // stage W: 96x128 fp16
      int o = s >> 4, cg = s & 15;
      *(uint4*)&Wl[o*128 + ((cg ^ (o & 15)) << 3)] =
          *(const uint4*)&WTh[(k*96 + o)*128 + (cg << 3)];
    }
    {                                         // stage B: shifted fp16 rows
      const int cq = t & 15, vi0 = t >> 4;
      #pragma unroll
      for (int p = 0; p < 4; ++p) {
        int vl = (p << 4) + vi0;
        int v  = vb + vl;
        int z = v / HW, y = (v / DS) % DS, xx = v % DS;
        int zz = z + dz, yy = y + dy, xq = xx + dx;
        uint4 pk = {0u,0u,0u,0u};
        if ((unsigned)zz < 24u && (unsigned)yy < 24u && (unsigned)xq < 24u)
          pk = *(const uint4*)&A2th[(v + doff)*CH + (cq << 3)];
        *(uint4*)&Bl[vl*128 + ((cq ^ (vl & 15)) << 3)] = pk;
      }
    }
    __syncthreads();
    #pragma unroll
    for (int ks = 0; ks < 4; ++ks) {
      int gx = (((ks << 2) + quad) ^ l16) << 3;
      f16x8 b = *(const f16x8*)&Bl[((w << 4) + l16)*128 + gx];
      #pragma unroll
      for (int m = 0; m < 6; ++m) {
        f16x8 a = *(const f16x8*)&Wl[((m << 4) + l16)*128 + gx];
        acc[m] = __builtin_amdgcn_mfma_f32_16x16x32_f16(a, b, acc[m], 0, 0, 0);
      }
    }
  }
  #pragma unroll
  for (int m = 0; m < 6; ++m)
    #pragma unroll
    for (int r = 0; r < 4; ++r) {
      int o = (m << 4) + (quad << 2) + r;      // D: row=quad*4+r, col=l16
      if (o < 81)
        OFFp[(kg*81 + o)*VS + vb + (w << 4) + l16] = (_Float16)acc[m][r];
    }
}

// ---------------------------------------------------------------------------
// K5: deformable conv via f16 MFMA.  grid = 216 v-tiles x 3 tap-groups
// (9 taps).  Meta (all 256 threads): per-corner packed (w,w) half2 + idx*128
// in one uint2.  Gather: 16B loads (8ch), v_pk_fma_f16, fp16 accum ->
// MFMA-ready, no converts.  fp16 partials D0..D2, no atomics.
// ---------------------------------------------------------------------------
__global__ __launch_bounds__(256) void deform_kernel(
    const _Float16* __restrict__ A2th, const _Float16* __restrict__ OFFp,
    const float* __restrict__ b_off, const _Float16* __restrict__ WDh,
    _Float16* __restrict__ D0, _Float16* __restrict__ D1,
    _Float16* __restrict__ D2) {
  const int vb = (blockIdx.x % 216) * 64;
  const int kg = blockIdx.x / 216;          // 0..2
  _Float16* DP = (kg == 0) ? D0 : (kg == 1) ? D1 : D2;
  __shared__ __align__(16) _Float16 Wl[128*128]; // 32 KB
  __shared__ __align__(16) _Float16 Bl[64*128];  // 16 KB
  __shared__ uint2 M[64][8];                     // 4 KB: (half2(w,w), idx*128)
  const int t    = threadIdx.x;
  const int lane = t & 63, w = t >> 6;
  const int l16  = lane & 15, quad = lane >> 4;
  f32x4 acc[2][4];
  #pragma unroll
  for (int i = 0; i < 2; ++i)
    #pragma unroll
    for (int n = 0; n < 4; ++n) acc[i][n] = (f32x4){0.f,0.f,0.f,0.f};

  for (int kk = 0; kk < 9; ++kk) {
    const int k = kg*9 + kk;
    __syncthreads();                          // previous tap consumed
    for (int s = t; s < 2048; s += 256) {     // stage W: 128x128 fp16
      int o = s >> 4, cg = s & 15;
      *(uint4*)&Wl[o*128 + ((cg ^ (o & 15)) << 3)] =
          *(const uint4*)&WDh[(k*CH + o)*CH + (cg << 3)];
    }
    {                                         // meta: 4 threads per voxel
      int vl = t >> 2, cp = t & 3;
      int v = vb + vl;
      int z = v / HW, y = (v / DS) % DS, xx = v % DS;
      float po[3];
      #pragma unroll
      for (int a = 0; a < 3; ++a) {
        int row = 3*k + a;
        po[a] = (float)OFFp[row*VS + v] + (float)OFFp[(81 + row)*VS + v]
              + (float)OFFp[(162 + row)*VS + v] + b_off[row];
      }
      float cz = (float)(z  + k/9     - 1) + po[0];
      float cy = (float)(y  + (k/3)%3 - 1) + po[1];
      float cx = (float)(xx + k%3     - 1) + po[2];
      float fz = floorf(cz), fy = floorf(cy), fx = floorf(cx);
      int iz = (int)fz, iy = (int)fy, ix = (int)fx;
      float rz = cz - fz, ry = cy - fy, rx = cx - fx;
      #pragma unroll
      for (int cc2 = 0; cc2 < 2; ++cc2) {
        int corner = cp*2 + cc2;
        int ca = corner >> 2, cb = (corner >> 1) & 1, cc = corner & 1;
        int zi = iz + ca, yi = iy + cb, xi = ix + cc;
        float ww = (ca ? rz : 1.f-rz) * (cb ? ry : 1.f-ry) * (cc ? rx : 1.f-rx);
        bool valid = ((unsigned)zi < 24u) && ((unsigned)yi < 24u) && ((unsigned)xi < 24u);
        float wv = valid ? ww : 0.f;
        half2v wp = {(_Float16)wv, (_Float16)wv};
        int idx = valid ? (zi*DS + yi)*DS + xi : 0;
        M[vl][corner] = make_uint2(h2u(wp), (unsigned)(idx << 7));
      }
    }
    __syncthreads();
    {                                         // gather: 16B loads + pk_fma
      const int cq = t & 15, vi0 = t >> 4;
      #pragma unroll
      for (int p = 0; p < 4; ++p) {
        int vl = (p << 4) + vi0;
        half2v a0 = {(_Float16)0.f, (_Float16)0.f};
        half2v a1 = a0, a2 = a0, a3 = a0;
        #pragma unroll
        for (int corner = 0; corner < 8; ++corner) {
          uint2 m = M[vl][corner];
          half2v wp = u2h(m.x);
          uint4 g = *(const uint4*)&A2th[m.y + (cq << 3)];
          a0 += u2h(g.x) * wp;
          a1 += u2h(g.y) * wp;
          a2 += u2h(g.z) * wp;
          a3 += u2h(g.w) * wp;
        }
        uint4 pk = {h2u(a0), h2u(a1), h2u(a2), h2u(a3)};
        *(uint4*)&Bl[vl*128 + ((cq ^ (vl & 15)) << 3)] = pk;
      }
    }
    __syncthreads();
    #pragma unroll
    for (int ks = 0; ks < 4; ++ks) {
      int gx = (((ks << 2) + quad) ^ l16) << 3;
      f16x8 a0 = *(const f16x8*)&Wl[((w << 5) + l16)*128 + gx];
      f16x8 a1 = *(const f16x8*)&Wl[((w << 5) + 16 + l16)*128 + gx];
      #pragma unroll
      for (int n = 0; n < 4; ++n) {
        f16x8 b = *(const f16x8*)&Bl[((n << 4) + l16)*128 + gx];
        acc[0][n] = __builtin_amdgcn_mfma_f32_16x16x32_f16(a0, b, acc[0][n], 0, 0, 0);
        acc[1][n] = __builtin_amdgcn_mfma_f32_16x16x32_f16(a1, b, acc[1][n], 0, 0, 0);
      }
    }
  }
  #pragma unroll
  for (int i = 0; i < 2; ++i)
    #pragma unroll
    for (int n = 0; n < 4; ++n)
      #pragma unroll
      for (int r = 0; r < 4; ++r) {
        int o = (w << 5) + (i << 4) + (quad << 2) + r;
        int v = vb + (n << 4) + l16;
        DP[o*VS + v] = (_Float16)acc[i][n][r];
      }
}

// ---------------------------------------------------------------------------
// K6: sum 3 fp16 DEF partials + b_def, 1x1x1 conv, + b1, multiply by x.
// ---------------------------------------------------------------------------
__global__ __launch_bounds__(256) void pw_mul_kernel(
    const _Float16* __restrict__ D0, const _Float16* __restrict__ D1,
    const _Float16* __restrict__ D2, const float* __restrict__ b_def,
    const float* __restrict__ W1T, const float* __restrict__ b1,
    const float* __restrict__ x, float* __restrict__ out) {
  const int vb = blockIdx.x * 32;
  __shared__ __align__(16) float Wl[64*128];  // 32 KB
  __shared__ __align__(16) float Bl[64*32];   // 8 KB
  const int t  = threadIdx.x;
  const int og = t / 8, vg = t % 8;
  const int o0 = og * 4;
  float acc[4][4];
  #pragma unroll
  for (int i = 0; i < 4; ++i)
    #pragma unroll
    for (int j = 0; j < 4; ++j) acc[i][j] = 0.f;

  for (int chh = 0; chh < 2; ++chh) {
    if (chh) __syncthreads();
    for (int s = t; s < 64*32; s += 256) {
      int cl = s / 32, oq = s % 32;
      *(float4*)&Wl[cl*128 + 4*oq] =
          *(const float4*)&W1T[(chh*64 + cl)*CH + 4*oq];
    }
    for (int s = t; s < 64*8; s += 256) {
      int cl = s / 8, vq = s % 8;
      int c  = chh*64 + cl;
      int idx = c*VS + vb + 4*vq;
      h4 a0 = *(const h4*)&D0[idx];
      h4 a1 = *(const h4*)&D1[idx];
      h4 a2 = *(const h4*)&D2[idx];
      float bd = b_def[c];
      *(float4*)&Bl[cl*32 + 4*vq] = make_float4(
          (float)a0.x + (float)a1.x + (float)a2.x + bd,
          (float)a0.y + (float)a1.y + (float)a2.y + bd,
          (float)a0.z + (float)a1.z + (float)a2.z + bd,
          (float)a0.w + (float)a1.w + (float)a2.w + bd);
    }
    __syncthreads();
    for (int cl = 0; cl < 64; ++cl) {
      float4 b  = *(const float4*)&Bl[cl*32 + 4*vg];
      float4 w  = *(const float4*)&Wl[cl*128 + o0];
      float wv[4] = {w.x,w.y,w.z,w.w};
      float bv[4] = {b.x,b.y,b.z,b.w};
      #pragma unroll
      for (int i = 0; i < 4; ++i)
        #pragma unroll
        for (int j = 0; j < 4; ++j)
          acc[i][j] = fmaf(wv[i], bv[j], acc[i][j]);
    }
  }
  #pragma unroll
  for (int i = 0; i < 4; ++i) {
    int o = o0 + i;
    float bias = b1[o];
    float4 xs = *(const float4*)&x[o*VS + vb + 4*vg];
    *(float4*)&out[o*VS + vb + 4*vg] =
        make_float4(xs.x*(acc[i][0]+bias), xs.y*(acc[i][1]+bias),
                    xs.z*(acc[i][2]+bias), xs.w*(acc[i][3]+bias));
  }
}

// ---------------------------------------------------------------------------
// Workspace (floats, total 5,622,016 f = 22.5 MB):
//   [0        , 1769472)  A1 fp32 (dw5 out) -> later D0,D1 fp16
//   [1769472  , 2654208)  A2th [V][128] fp16
//   [2654208  , 4333824)  OFFp [3][81][V] fp16
//   [4333824  , 5218560)  D2 fp16
//   [5218560  , 5622016)  WTh fp16 | WDh fp16 | W1T fp32
// ---------------------------------------------------------------------------
extern "C" void kernel_launch(void* const* d_in, const int* in_sizes, int n_in,
                              void* d_out, int out_size, void* d_ws, size_t ws_size,
                              hipStream_t stream) {
  (void)in_sizes; (void)n_in; (void)out_size; (void)ws_size;
  const float* x     = (const float*)d_in[0];
  const float* w0    = (const float*)d_in[1];
  const float* b0    = (const float*)d_in[2];
  const float* wsw   = (const float*)d_in[3];
  const float* bs    = (const float*)d_in[4];
  const float* w_off = (const float*)d_in[5];
  const float* b_off = (const float*)d_in[6];
  const float* w_def = (const float*)d_in[7];
  const float* b_def = (const float*)d_in[8];
  const float* w1    = (const float*)d_in[9];
  const float* b1    = (const float*)d_in[10];
  float* out = (float*)d_out;

  float* wsf = (float*)d_ws;
  float*     A1   = wsf;
  _Float16*  A2th = (_Float16*)(wsf + 1769472);
  _Float16*  OFFp = (_Float16*)(wsf + 2654208);
  _Float16*  D2   = (_Float16*)(wsf + 4333824);
  _Float16*  WTh  = (_Float16*)(wsf + 5218560);
  _Float16*  WDh  = WTh + 331776;
  float*     W1T  = (float*)(WDh + 442368);
  _Float16*  D0   = (_Float16*)A1;          // A1 dead after dwdil
  _Float16*  D1   = D0 + 128*VS;

  prep_weights  <<<228, 256, 0, stream>>>(w_off, w_def, w1, WTh, WDh, W1T);
  dw5_kernel    <<<512, 256, 0, stream>>>(x, w0, b0, A1);
  dwdil_kernel  <<<512, 256, 0, stream>>>(A1, wsw, bs, A2th);
  offconv_kernel<<<648, 256, 0, stream>>>(A2th, WTh, OFFp);
  deform_kernel <<<648, 256, 0, stream>>>(A2th, OFFp, b_off, WDh, D0, D1, D2);
  pw_mul_kernel <<<432, 256, 0, stream>>>(D0, D1, D2, b_def, W1T, b1, x, out);
}